// Round 3
// baseline (2931.268 us; speedup 1.0000x reference)
//
#include <hip/hip_runtime.h>
#include <hip/hip_bf16.h>

// ---------------------------------------------------------------------------
// GraphEncoder (VGAE-style GCN x2 + reparam). FP32 in/out (per harness
// contract: reference dtype float32 -> const float*), edge_index int32.
// Aggregate-first form (Anorm @ (X@W) == (Anorm@X) @ W):
//   dis = rsqrt(deg+1)
//   xa  = scatter(x)+x*dis^2        (fp32 atomics into ws bufA)
//   h   = xa@W1+b1                  (bf16 MFMA, fp32 IO, in-place over bufA)
//   ha  = scatter(h)+h*dis^2        (agg scratch = d_out; ha -> bufA in place)
//   [mu|ls] = ha@[Wmu|Wls]+[bmu|bls] -> d_out[NO..3NO)
//   z = mu + eps*exp(ls)            -> d_out[0..NO)
// WS: dis(400KB) + Wcat/bcat(65KB) + bufA(51.2MB) ~= 52.3 MB.
// ---------------------------------------------------------------------------

typedef unsigned int u32;
typedef unsigned short u16;
typedef __bf16 bf16x8 __attribute__((ext_vector_type(8)));
typedef float f32x4 __attribute__((ext_vector_type(4)));

__device__ __forceinline__ u16 f2bf(float f) {  // fp32 -> bf16 RNE
    union { float f; u32 u; } v; v.f = f;
    u32 u = v.u;
    u += 0x7fffu + ((u >> 16) & 1u);
    return (u16)(u >> 16);
}

// ---------------- degree histogram + rsqrt ----------------
__global__ __launch_bounds__(256) void deg_kernel(const int* __restrict__ dst,
                                                  float* __restrict__ deg, int E) {
    int i = blockIdx.x * 256 + threadIdx.x;
    if (i < E) unsafeAtomicAdd(&deg[dst[i]], 1.0f);
}

__global__ __launch_bounds__(256) void rsqrt_kernel(float* __restrict__ deg, int N) {
    int i = blockIdx.x * 256 + threadIdx.x;
    if (i < N) deg[i] = rsqrtf(deg[i] + 1.0f);
}

// ---------------- pack Wcat = [Wmu | Wls], bcat = [bmu | bls] (fp32) --------
__global__ __launch_bounds__(256) void pack_wcat(const float* __restrict__ Wmu,
                                                 const float* __restrict__ Wls,
                                                 const float* __restrict__ bmu,
                                                 const float* __restrict__ bls,
                                                 float* __restrict__ Wcat,
                                                 float* __restrict__ bcat) {
    int idx = blockIdx.x * 256 + threadIdx.x;  // 16384
    if (idx < 16384) {
        int k = idx >> 7, n = idx & 127;
        Wcat[idx] = (n < 64) ? Wmu[k * 64 + n] : Wls[k * 64 + (n - 64)];
    }
    if (idx < 128) bcat[idx] = (idx < 64) ? bmu[idx] : bls[idx - 64];
}

// ---------------- edge scatter: agg[dst] += feat[src]*dis[s]*dis[d] ---------
// One wave per edge; lane handles 2 fp32 features (float2, 8B coalesced).
__global__ __launch_bounds__(256) void scatter_kernel(const float* __restrict__ feat,
                                                      const int* __restrict__ src,
                                                      const int* __restrict__ dst,
                                                      const float* __restrict__ dis,
                                                      float* __restrict__ agg, int E) {
    int lane = threadIdx.x & 63;
    int gwave = (blockIdx.x * blockDim.x + threadIdx.x) >> 6;
    int nwaves = (gridDim.x * blockDim.x) >> 6;
    for (int e = gwave; e < E; e += nwaves) {
        int s = src[e], d = dst[e];
        float norm = dis[s] * dis[d];
        float2 v = *(const float2*)(feat + (long)s * 128 + 2 * lane);
        float* row = agg + (long)d * 128 + 2 * lane;
        unsafeAtomicAdd(row, v.x * norm);
        unsafeAtomicAdd(row + 1, v.y * norm);
    }
}

// ---------------- self-loop add: acc[i] = agg[i] + feat[i]*dis^2 ------------
// acc may alias agg or feat (elementwise same index -> safe).
__global__ __launch_bounds__(256) void selfloop_kernel(const float* agg,
                                                       const float* feat,
                                                       const float* __restrict__ dis,
                                                       float* acc, long NE2) {
    long tid = (long)blockIdx.x * 256 + threadIdx.x;  // N*64, 2 feats each
    if (tid >= NE2) return;
    long i = tid >> 6;
    float d2 = dis[i] * dis[i];
    float2 f = *(const float2*)(feat + i * 128 + (tid & 63) * 2);
    float2 a = *(const float2*)(agg + i * 128 + (tid & 63) * 2);
    float2 r = make_float2(a.x + f.x * d2, a.y + f.y * d2);
    *(float2*)(acc + i * 128 + (tid & 63) * 2) = r;
}

// ---------------- C[M,128] = A[M,128]@B[128,128] + bias (fp32 IO) -----------
// Internally bf16 MFMA 16x16x32. Split-col store: col<64 -> P0[row*RS+col],
// else P1[row*RS+col-64]. Layer1 runs in place (P0=A, P1=A+64, RS=128): each
// wave reads only its own 16 rows before storing them; A/P0/P1 NOT restrict.
__global__ __launch_bounds__(256) void gemm128(const float* A, const float* B,
                                               const float* __restrict__ bias,
                                               float* P0, float* P1, int RS, int M) {
    __shared__ __align__(16) u16 Bt[128][136];  // B^T as bf16, +8 pad
    __shared__ float biasS[128];
    int tid = threadIdx.x;
    for (int idx = tid; idx < 128 * 128; idx += 256) {
        int k = idx >> 7, n = idx & 127;
        Bt[n][k] = f2bf(B[idx]);
    }
    if (tid < 128) biasS[tid] = bias[tid];
    __syncthreads();

    int wave = tid >> 6, lane = tid & 63;
    int quad = lane >> 4, mn = lane & 15;
    long row0 = (long)blockIdx.x * 64 + wave * 16;
    if (row0 >= M) return;

    // A frags: A[m=row0+mn][k = kk*32 + quad*8 + j], fp32 -> bf16
    bf16x8 afrag[4];
    const float* Arow = A + (row0 + mn) * 128 + quad * 8;
#pragma unroll
    for (int kk = 0; kk < 4; ++kk) {
        f32x4 lo = *(const f32x4*)(Arow + kk * 32);
        f32x4 hi = *(const f32x4*)(Arow + kk * 32 + 4);
        union { bf16x8 v; u16 s[8]; } a;
#pragma unroll
        for (int j = 0; j < 4; ++j) { a.s[j] = f2bf(lo[j]); a.s[4 + j] = f2bf(hi[j]); }
        afrag[kk] = a.v;
    }

#pragma unroll
    for (int n0 = 0; n0 < 8; ++n0) {
        f32x4 acc = {0.f, 0.f, 0.f, 0.f};
#pragma unroll
        for (int kk = 0; kk < 4; ++kk) {
            bf16x8 bfrag =
                *reinterpret_cast<const bf16x8*>(&Bt[n0 * 16 + mn][kk * 32 + quad * 8]);
            acc = __builtin_amdgcn_mfma_f32_16x16x32_bf16(afrag[kk], bfrag, acc, 0, 0, 0);
        }
        int col = n0 * 16 + mn;  // C/D: col=lane&15 (+16*n0), row=quad*4+reg
        float* base = (col < 64) ? P0 : P1;
#pragma unroll
        for (int r = 0; r < 4; ++r)
            base[(row0 + quad * 4 + r) * (long)RS + (col & 63)] = acc[r] + biasS[col];
    }
}

// ---------------- reparam: z = mu + eps*exp(ls) -----------------------------
__global__ __launch_bounds__(256) void reparam(float* __restrict__ out,
                                               const float* __restrict__ eps, long NO) {
    long tid = (long)blockIdx.x * 256 + threadIdx.x;
    if (tid >= NO) return;
    float mu = out[NO + tid];
    float ls = out[2 * NO + tid];
    out[tid] = mu + eps[tid] * expf(fminf(ls, 30.f));
}

// ---------------------------------------------------------------------------
extern "C" void kernel_launch(void* const* d_in, const int* in_sizes, int n_in,
                              void* d_out, int out_size, void* d_ws, size_t ws_size,
                              hipStream_t stream) {
    const float* x   = (const float*)d_in[0];
    const int* ei    = (const int*)d_in[1];
    const float* W1  = (const float*)d_in[2];
    const float* b1  = (const float*)d_in[3];
    const float* Wmu = (const float*)d_in[4];
    const float* bmu = (const float*)d_in[5];
    const float* Wls = (const float*)d_in[6];
    const float* bls = (const float*)d_in[7];
    const float* eps = (const float*)d_in[8];
    float* out = (float*)d_out;

    const int N = in_sizes[0] / 128;   // 100000
    const int E = in_sizes[1] / 2;     // 1600000
    const int* src = ei;
    const int* dst = ei + E;
    const long NO = (long)N * 64;      // 6.4M
    const long NE2 = (long)N * 64;     // threads for 2-wide feature kernels

    // Workspace: dis f32[N] @0 ; Wcat f32[16384]+bcat f32[128] @512K ;
    //            bufA f32[N*128] @1M  (total ~52.3 MB)
    char* ws = (char*)d_ws;
    float* dis  = (float*)(ws);
    float* wcat = (float*)(ws + (1 << 19));
    float* bcat = wcat + 16384;
    float* bufA = (float*)(ws + (1 << 20));

    const size_t aggBytes = (size_t)N * 128 * sizeof(float);

    hipMemsetAsync(dis, 0, (size_t)N * sizeof(float), stream);
    hipMemsetAsync(bufA, 0, aggBytes, stream);
    hipMemsetAsync(out, 0, aggBytes, stream);  // out[0..N*128) doubles as agg2

    deg_kernel<<<(E + 255) / 256, 256, 0, stream>>>(dst, dis, E);
    rsqrt_kernel<<<(N + 255) / 256, 256, 0, stream>>>(dis, N);
    pack_wcat<<<64, 256, 0, stream>>>(Wmu, Wls, bmu, bls, wcat, bcat);

    int gridF = (int)((NE2 + 255) / 256);
    int gemmBlocks = (N + 63) / 64;

    // Layer 1: xa = Anorm@x (into bufA); h = xa@W1 + b1 (in-place bufA)
    scatter_kernel<<<4096, 256, 0, stream>>>(x, src, dst, dis, bufA, E);
    selfloop_kernel<<<gridF, 256, 0, stream>>>(bufA, x, dis, bufA, NE2);
    gemm128<<<gemmBlocks, 256, 0, stream>>>(bufA, W1, b1, bufA, bufA + 64, 128, N);

    // Layer 2: ha = Anorm@h (agg in out-scratch, ha -> bufA in place);
    //          [mu|ls] = ha@Wcat + bcat -> out[NO..3NO)
    scatter_kernel<<<4096, 256, 0, stream>>>(bufA, src, dst, dis, out, E);
    selfloop_kernel<<<gridF, 256, 0, stream>>>(out, bufA, dis, bufA, NE2);
    gemm128<<<gemmBlocks, 256, 0, stream>>>(bufA, wcat, bcat, out + NO, out + 2 * NO,
                                            64, N);

    // z = mu + eps*exp(ls) -> out[0..NO)
    reparam<<<(int)((NO + 255) / 256), 256, 0, stream>>>(out, eps, NO);
}

// Round 4
// 663.975 us; speedup vs baseline: 4.4147x; 4.4147x over previous
//
#include <hip/hip_runtime.h>
#include <hip/hip_bf16.h>

// ---------------------------------------------------------------------------
// GraphEncoder (VGAE 2-layer GCN + reparam), fp32 in/out, edge_index int32.
// Round 4: scatter-atomics (157 G f32 atomics/s bound, 2x1300us) replaced by
// CSR build + per-node register gather (zero float atomics).
//   deg/dis -> CSR(dst) -> xa = gather(x) -> h = xa@W1+b1 (in-place MFMA)
//   g = h@Wcat (in-place) -> gather(g)+bcat+self -> mu|ls -> fused reparam.
// WS ~60 MB. Only memset: deg (400 KB).
// ---------------------------------------------------------------------------

typedef unsigned int u32;
typedef unsigned short u16;
typedef __bf16 bf16x8 __attribute__((ext_vector_type(8)));
typedef float f32x4 __attribute__((ext_vector_type(4)));

__device__ __forceinline__ u16 f2bf(float f) {  // fp32 -> bf16 RNE
    union { float f; u32 u; } v; v.f = f;
    u32 u = v.u;
    u += 0x7fffu + ((u >> 16) & 1u);
    return (u16)(u >> 16);
}

// ---------------- degree histogram (u32) ----------------
__global__ __launch_bounds__(256) void deg_hist(const int* __restrict__ dst,
                                                u32* __restrict__ deg, int E) {
    int i = blockIdx.x * 256 + threadIdx.x;
    if (i < E) atomicAdd(&deg[dst[i]], 1u);
}

// ---------------- scan A: per-block totals ----------------
__global__ __launch_bounds__(256) void scanA(const u32* __restrict__ deg,
                                             u32* __restrict__ blockSums, int N) {
    __shared__ u32 s[256];
    int t = threadIdx.x, i = blockIdx.x * 256 + t;
    s[t] = (i < N) ? deg[i] : 0u;
    for (int off = 128; off > 0; off >>= 1) {
        __syncthreads();
        if (t < off) s[t] += s[t + off];
    }
    if (t == 0) blockSums[blockIdx.x] = s[0];
}

// ---------------- scan B: exclusive scan of block totals (1 block) ----------
__global__ __launch_bounds__(512) void scanB(const u32* __restrict__ blockSums,
                                             u32* __restrict__ blockOffs, int NB) {
    __shared__ u32 s[512];
    int t = threadIdx.x;
    u32 v = (t < NB) ? blockSums[t] : 0u;
    s[t] = v;
    for (int off = 1; off < 512; off <<= 1) {
        __syncthreads();
        u32 add = (t >= off) ? s[t - off] : 0u;
        __syncthreads();
        s[t] += add;
    }
    __syncthreads();
    if (t < NB) blockOffs[t] = s[t] - v;  // exclusive
}

// ---------------- scan C: rowstart/cursor/dis ----------------
__global__ __launch_bounds__(256) void scanC(const u32* __restrict__ deg,
                                             const u32* __restrict__ blockOffs,
                                             u32* __restrict__ rowstart,
                                             u32* __restrict__ cursor,
                                             float* __restrict__ dis, int N, int E) {
    __shared__ u32 s[256];
    int t = threadIdx.x, i = blockIdx.x * 256 + t;
    u32 v = (i < N) ? deg[i] : 0u;
    s[t] = v;
    for (int off = 1; off < 256; off <<= 1) {
        __syncthreads();
        u32 add = (t >= off) ? s[t - off] : 0u;
        __syncthreads();
        s[t] += add;
    }
    __syncthreads();
    if (i < N) {
        u32 rs = blockOffs[blockIdx.x] + s[t] - v;  // exclusive
        rowstart[i] = rs;
        cursor[i] = rs;
        dis[i] = rsqrtf((float)v + 1.0f);
    }
    if (i == 0) rowstart[N] = (u32)E;
}

// ---------------- CSR placement ----------------
__global__ __launch_bounds__(256) void place_kernel(const int* __restrict__ src,
                                                    const int* __restrict__ dst,
                                                    u32* __restrict__ cursor,
                                                    int* __restrict__ csr, int E) {
    int i = blockIdx.x * 256 + threadIdx.x;
    if (i < E) {
        u32 pos = atomicAdd(&cursor[dst[i]], 1u);
        csr[pos] = src[i];
    }
}

// ---------------- pack Wcat=[Wmu|Wls], bcat=[bmu|bls], zbias=0 --------------
__global__ __launch_bounds__(256) void pack_wcat(const float* __restrict__ Wmu,
                                                 const float* __restrict__ Wls,
                                                 const float* __restrict__ bmu,
                                                 const float* __restrict__ bls,
                                                 float* __restrict__ Wcat,
                                                 float* __restrict__ bcat,
                                                 float* __restrict__ zbias) {
    int idx = blockIdx.x * 256 + threadIdx.x;  // 16384
    if (idx < 16384) {
        int k = idx >> 7, n = idx & 127;
        Wcat[idx] = (n < 64) ? Wmu[k * 64 + n] : Wls[k * 64 + (n - 64)];
    }
    if (idx < 128) {
        bcat[idx] = (idx < 64) ? bmu[idx] : bls[idx - 64];
        zbias[idx] = 0.0f;
    }
}

// ---------------- gather1: outbuf[d] = sum_s x[s]*dis[s]*dis[d] + x[d]*dd^2 -
// One wave per node; lane holds 2 features (float2, coalesced 512B rows).
__global__ __launch_bounds__(256) void gather1(const float* __restrict__ feat,
                                               const int* __restrict__ csr,
                                               const u32* __restrict__ rowstart,
                                               const float* __restrict__ dis,
                                               float* __restrict__ outbuf, int N) {
    int node = (blockIdx.x * 256 + threadIdx.x) >> 6;
    if (node >= N) return;
    int lane = threadIdx.x & 63;
    const float2* f2 = (const float2*)feat;
    float dd = dis[node];
    u32 beg = rowstart[node], end = rowstart[node + 1];
    float2 self = f2[(long)node * 64 + lane];
    float2 acc = make_float2(self.x * dd * dd, self.y * dd * dd);
    for (u32 e0 = beg; e0 < end; e0 += 64) {
        int s = 0; float ds = 0.f;
        if (e0 + (u32)lane < end) { s = csr[e0 + lane]; ds = dis[s]; }
        int cnt = (int)min(64u, end - e0);
        for (int j = 0; j < cnt; ++j) {
            int sj = __shfl(s, j);
            float nj = __shfl(ds, j) * dd;
            float2 v = f2[(long)sj * 64 + lane];
            acc.x += v.x * nj;
            acc.y += v.y * nj;
        }
    }
    ((float2*)outbuf)[(long)node * 64 + lane] = acc;
}

// ---------------- gather2 + bias + fused reparam ----------------------------
// acc(d) = sum_s g[s]*norm + g[d]*dd^2 + bcat ; lanes 0..31 = mu cols,
// lanes 32..63 = ls cols; z = mu + eps*exp(ls) via cross-half shfl.
__global__ __launch_bounds__(256) void gather2(const float* __restrict__ g,
                                               const int* __restrict__ csr,
                                               const u32* __restrict__ rowstart,
                                               const float* __restrict__ dis,
                                               const float* __restrict__ bcat,
                                               const float* __restrict__ eps,
                                               float* __restrict__ out, int N) {
    int node = (blockIdx.x * 256 + threadIdx.x) >> 6;
    if (node >= N) return;
    int lane = threadIdx.x & 63;
    const float2* f2 = (const float2*)g;
    float dd = dis[node];
    u32 beg = rowstart[node], end = rowstart[node + 1];
    float2 self = f2[(long)node * 64 + lane];
    float2 acc = make_float2(self.x * dd * dd, self.y * dd * dd);
    for (u32 e0 = beg; e0 < end; e0 += 64) {
        int s = 0; float ds = 0.f;
        if (e0 + (u32)lane < end) { s = csr[e0 + lane]; ds = dis[s]; }
        int cnt = (int)min(64u, end - e0);
        for (int j = 0; j < cnt; ++j) {
            int sj = __shfl(s, j);
            float nj = __shfl(ds, j) * dd;
            float2 v = f2[(long)sj * 64 + lane];
            acc.x += v.x * nj;
            acc.y += v.y * nj;
        }
    }
    float2 b = ((const float2*)bcat)[lane];
    acc.x += b.x;
    acc.y += b.y;
    long NO = (long)N * 64;
    float ox = __shfl(acc.x, (lane + 32) & 63);  // ls pair (valid for lane<32)
    float oy = __shfl(acc.y, (lane + 32) & 63);
    if (lane < 32) {
        ((float2*)(out + NO))[(long)node * 32 + lane] = acc;  // mu
        float2 e2 = ((const float2*)eps)[(long)node * 32 + lane];
        float2 z = make_float2(acc.x + e2.x * __expf(ox), acc.y + e2.y * __expf(oy));
        ((float2*)out)[(long)node * 32 + lane] = z;           // z
    } else {
        ((float2*)(out + 2 * NO))[(long)node * 32 + (lane - 32)] = acc;  // logstd
    }
}

// ---------------- C[M,128] = A[M,128]@B[128,128] + bias (fp32 IO) -----------
// bf16 MFMA 16x16x32 inside. In-place safe: each wave reads only its own 16
// rows before storing them (A/P0/P1 intentionally NOT __restrict__).
__global__ __launch_bounds__(256) void gemm128(const float* A, const float* B,
                                               const float* __restrict__ bias,
                                               float* P0, float* P1, int RS, int M) {
    __shared__ __align__(16) u16 Bt[128][136];  // B^T as bf16, +8 pad
    __shared__ float biasS[128];
    int tid = threadIdx.x;
    for (int idx = tid; idx < 128 * 128; idx += 256) {
        int k = idx >> 7, n = idx & 127;
        Bt[n][k] = f2bf(B[idx]);
    }
    if (tid < 128) biasS[tid] = bias[tid];
    __syncthreads();

    int wave = tid >> 6, lane = tid & 63;
    int quad = lane >> 4, mn = lane & 15;
    long row0 = (long)blockIdx.x * 64 + wave * 16;
    if (row0 >= M) return;

    bf16x8 afrag[4];  // A[m=row0+mn][k = kk*32 + quad*8 + j]
    const float* Arow = A + (row0 + mn) * 128 + quad * 8;
#pragma unroll
    for (int kk = 0; kk < 4; ++kk) {
        f32x4 lo = *(const f32x4*)(Arow + kk * 32);
        f32x4 hi = *(const f32x4*)(Arow + kk * 32 + 4);
        union { bf16x8 v; u16 s[8]; } a;
#pragma unroll
        for (int j = 0; j < 4; ++j) { a.s[j] = f2bf(lo[j]); a.s[4 + j] = f2bf(hi[j]); }
        afrag[kk] = a.v;
    }

#pragma unroll
    for (int n0 = 0; n0 < 8; ++n0) {
        f32x4 acc = {0.f, 0.f, 0.f, 0.f};
#pragma unroll
        for (int kk = 0; kk < 4; ++kk) {
            bf16x8 bfrag =
                *reinterpret_cast<const bf16x8*>(&Bt[n0 * 16 + mn][kk * 32 + quad * 8]);
            acc = __builtin_amdgcn_mfma_f32_16x16x32_bf16(afrag[kk], bfrag, acc, 0, 0, 0);
        }
        int col = n0 * 16 + mn;  // C/D: col=lane&15(+16*n0), row=quad*4+reg
        float* base = (col < 64) ? P0 : P1;
#pragma unroll
        for (int r = 0; r < 4; ++r)
            base[(row0 + quad * 4 + r) * (long)RS + (col & 63)] = acc[r] + biasS[col];
    }
}

// ---------------------------------------------------------------------------
extern "C" void kernel_launch(void* const* d_in, const int* in_sizes, int n_in,
                              void* d_out, int out_size, void* d_ws, size_t ws_size,
                              hipStream_t stream) {
    const float* x   = (const float*)d_in[0];
    const int* ei    = (const int*)d_in[1];
    const float* W1  = (const float*)d_in[2];
    const float* b1  = (const float*)d_in[3];
    const float* Wmu = (const float*)d_in[4];
    const float* bmu = (const float*)d_in[5];
    const float* Wls = (const float*)d_in[6];
    const float* bls = (const float*)d_in[7];
    const float* eps = (const float*)d_in[8];
    float* out = (float*)d_out;

    const int N = in_sizes[0] / 128;   // 100000
    const int E = in_sizes[1] / 2;     // 1600000
    const int* src = ei;
    const int* dst = ei + E;
    const int NB = (N + 255) / 256;    // 391 scan blocks

    // WS layout (bytes), total ~59.6 MB:
    char* ws = (char*)d_ws;
    u32* deg      = (u32*)(ws + 0);          // 400,000
    u32* rowstart = (u32*)(ws + 401408);     // 400,004 (N+1)
    u32* cursor   = (u32*)(ws + 802816);     // 400,000
    u32* blockSums= (u32*)(ws + 1204224);    // 2,048
    u32* blockOffs= (u32*)(ws + 1206272);    // 2,048
    float* dis    = (float*)(ws + 1208320);  // 400,000
    float* wcat   = (float*)(ws + 1610752);  // 65,536
    float* bcat   = (float*)(ws + 1676288);  // 512
    float* zbias  = (float*)(ws + 1676800);  // 512
    int* csr      = (int*)(ws + 1677312);    // 6,400,000
    float* bufA   = (float*)(ws + 8388608);  // 51,200,000

    hipMemsetAsync(deg, 0, (size_t)N * sizeof(u32), stream);

    int gridE = (E + 255) / 256;
    deg_hist<<<gridE, 256, 0, stream>>>(dst, deg, E);
    scanA<<<NB, 256, 0, stream>>>(deg, blockSums, N);
    scanB<<<1, 512, 0, stream>>>(blockSums, blockOffs, NB);
    scanC<<<NB, 256, 0, stream>>>(deg, blockOffs, rowstart, cursor, dis, N, E);
    place_kernel<<<gridE, 256, 0, stream>>>(src, dst, cursor, csr, E);
    pack_wcat<<<64, 256, 0, stream>>>(Wmu, Wls, bmu, bls, wcat, bcat, zbias);

    int gridG = (N * 64 + 255) / 256;  // 1 wave/node, 4 nodes/block
    int gemmBlocks = (N + 63) / 64;

    // Layer 1: xa = Anorm@x (gather) ; h = xa@W1 + b1 (in-place)
    gather1<<<gridG, 256, 0, stream>>>(x, csr, rowstart, dis, bufA, N);
    gemm128<<<gemmBlocks, 256, 0, stream>>>(bufA, W1, b1, bufA, bufA + 64, 128, N);

    // Layer 2: g = h@Wcat (in-place, no bias) ; gather+bias+reparam -> out
    gemm128<<<gemmBlocks, 256, 0, stream>>>(bufA, wcat, zbias, bufA, bufA + 64, 128, N);
    gather2<<<gridG, 256, 0, stream>>>(bufA, csr, rowstart, dis, bcat, eps, out, N);
}

// Round 5
// 519.383 us; speedup vs baseline: 5.6437x; 1.2784x over previous
//
#include <hip/hip_runtime.h>
#include <hip/hip_bf16.h>

// ---------------------------------------------------------------------------
// GraphEncoder (VGAE 2-layer GCN + reparam), fp32 in/out, edge_index int32.
// Round 5: the network is LINEAR (no activation) ->
//   [mu|ls] = Anorm@((Anorm@x)@Wf) + r (x) bb + bcat,  Wf=W1@[Wmu|Wls],
//   bb=b1@[Wmu|Wls], r_d = dis_d*sum_{s in N(d)} dis_s + dis_d^2.
// One 128x128 GEMM instead of two. Features carried in bf16 (256B rows ->
// half the gather bytes/edge), fp32 accumulation. CSR build without the
// atomic->store chain (deg_hist records per-edge local offset).
// WS ~65.7 MB.
// ---------------------------------------------------------------------------

typedef unsigned int u32;
typedef unsigned short u16;
typedef __bf16 bf16x8 __attribute__((ext_vector_type(8)));
typedef float f32x4 __attribute__((ext_vector_type(4)));

__device__ __forceinline__ u16 f2bf(float f) {  // fp32 -> bf16 RNE
    union { float f; u32 u; } v; v.f = f;
    u32 u = v.u;
    u += 0x7fffu + ((u >> 16) & 1u);
    return (u16)(u >> 16);
}
__device__ __forceinline__ float bflo(u32 p) {
    union { u32 u; float f; } v; v.u = p << 16; return v.f;
}
__device__ __forceinline__ float bfhi(u32 p) {
    union { u32 u; float f; } v; v.u = p & 0xffff0000u; return v.f;
}

// ---------------- degree histogram + per-edge local offset ----------------
__global__ __launch_bounds__(256) void deg_hist(const int* __restrict__ dst,
                                                u32* __restrict__ deg,
                                                u32* __restrict__ loc, int E) {
    int i = blockIdx.x * 256 + threadIdx.x;
    if (i < E) loc[i] = atomicAdd(&deg[dst[i]], 1u);
}

// ---------------- scan A: per-block totals ----------------
__global__ __launch_bounds__(256) void scanA(const u32* __restrict__ deg,
                                             u32* __restrict__ blockSums, int N) {
    __shared__ u32 s[256];
    int t = threadIdx.x, i = blockIdx.x * 256 + t;
    s[t] = (i < N) ? deg[i] : 0u;
    for (int off = 128; off > 0; off >>= 1) {
        __syncthreads();
        if (t < off) s[t] += s[t + off];
    }
    if (t == 0) blockSums[blockIdx.x] = s[0];
}

// ---------------- scan B: exclusive scan of block totals (1 block) ----------
__global__ __launch_bounds__(512) void scanB(const u32* __restrict__ blockSums,
                                             u32* __restrict__ blockOffs, int NB) {
    __shared__ u32 s[512];
    int t = threadIdx.x;
    u32 v = (t < NB) ? blockSums[t] : 0u;
    s[t] = v;
    for (int off = 1; off < 512; off <<= 1) {
        __syncthreads();
        u32 add = (t >= off) ? s[t - off] : 0u;
        __syncthreads();
        s[t] += add;
    }
    __syncthreads();
    if (t < NB) blockOffs[t] = s[t] - v;  // exclusive
}

// ---------------- scan C: rowstart + dis ----------------
__global__ __launch_bounds__(256) void scanC(const u32* __restrict__ deg,
                                             const u32* __restrict__ blockOffs,
                                             u32* __restrict__ rowstart,
                                             float* __restrict__ dis, int N, int E) {
    __shared__ u32 s[256];
    int t = threadIdx.x, i = blockIdx.x * 256 + t;
    u32 v = (i < N) ? deg[i] : 0u;
    s[t] = v;
    for (int off = 1; off < 256; off <<= 1) {
        __syncthreads();
        u32 add = (t >= off) ? s[t - off] : 0u;
        __syncthreads();
        s[t] += add;
    }
    __syncthreads();
    if (i < N) {
        rowstart[i] = blockOffs[blockIdx.x] + s[t] - v;  // exclusive
        dis[i] = rsqrtf((float)v + 1.0f);
    }
    if (i == 0) rowstart[N] = (u32)E;
}

// ---------------- CSR placement (no atomics) ----------------
__global__ __launch_bounds__(256) void place_kernel(const int* __restrict__ src,
                                                    const int* __restrict__ dst,
                                                    const u32* __restrict__ loc,
                                                    const u32* __restrict__ rowstart,
                                                    int* __restrict__ csr, int E) {
    int i = blockIdx.x * 256 + threadIdx.x;
    if (i < E) csr[rowstart[dst[i]] + loc[i]] = src[i];
}

// ---------------- fuse weights: Wf = W1@[Wmu|Wls], bb = b1@[Wmu|Wls] --------
__global__ __launch_bounds__(256) void fuse_w(const float* __restrict__ W1,
                                              const float* __restrict__ Wmu,
                                              const float* __restrict__ Wls,
                                              const float* __restrict__ b1,
                                              const float* __restrict__ bmu,
                                              const float* __restrict__ bls,
                                              float* __restrict__ Wf,
                                              float* __restrict__ bb,
                                              float* __restrict__ bcat) {
    int idx = blockIdx.x * 256 + threadIdx.x;  // 16384
    if (idx >= 16384) return;
    int k = idx >> 7, n = idx & 127;
    const float* Wcol = (n < 64) ? (Wmu + n) : (Wls + (n - 64));
    float acc = 0.f;
#pragma unroll 8
    for (int j = 0; j < 128; ++j) acc += W1[k * 128 + j] * Wcol[j * 64];
    Wf[idx] = acc;
    if (k == 0) {
        float accb = 0.f;
#pragma unroll 8
        for (int j = 0; j < 128; ++j) accb += b1[j] * Wcol[j * 64];
        bb[n] = accb;
        bcat[n] = (n < 64) ? bmu[n] : bls[n - 64];
    }
}

// ---------------- x (fp32) -> xb (bf16 packed u32 pairs) --------------------
__global__ __launch_bounds__(256) void convert_x(const float* __restrict__ x,
                                                 u32* __restrict__ xb, long Q) {
    long i = (long)blockIdx.x * 256 + threadIdx.x;  // Q = N*128/4
    if (i >= Q) return;
    f32x4 v = ((const f32x4*)x)[i];
    u32 p0 = (u32)f2bf(v[0]) | ((u32)f2bf(v[1]) << 16);
    u32 p1 = (u32)f2bf(v[2]) | ((u32)f2bf(v[3]) << 16);
    ((uint2*)xb)[i] = make_uint2(p0, p1);
}

// ---------------- gather1: y = Anorm@x (bf16 rows), also r_d ----------------
// One wave per node; lane holds 2 features (one u32 = 2 bf16).
__global__ __launch_bounds__(256) void gather1(const u32* __restrict__ xb,
                                               const int* __restrict__ csr,
                                               const u32* __restrict__ rowstart,
                                               const float* __restrict__ dis,
                                               u32* __restrict__ yb,
                                               float* __restrict__ r, int N) {
    int node = (blockIdx.x * 256 + threadIdx.x) >> 6;
    if (node >= N) return;
    int lane = threadIdx.x & 63;
    float dd = dis[node];
    u32 beg = rowstart[node], end = rowstart[node + 1];
    u32 sv = xb[(long)node * 64 + lane];
    float accx = bflo(sv) * dd * dd, accy = bfhi(sv) * dd * dd;
    float rr = 0.f;
    for (u32 e0 = beg; e0 < end; e0 += 64) {
        int s = 0; float ds = 0.f;
        if (e0 + (u32)lane < end) { s = csr[e0 + lane]; ds = dis[s]; }
        int cnt = (int)min(64u, end - e0);
#pragma unroll 4
        for (int j = 0; j < cnt; ++j) {
            int sj = __shfl(s, j);
            float nj = __shfl(ds, j) * dd;
            rr += nj;
            u32 w = xb[(long)sj * 64 + lane];
            accx += bflo(w) * nj;
            accy += bfhi(w) * nj;
        }
    }
    yb[(long)node * 64 + lane] = (u32)f2bf(accx) | ((u32)f2bf(accy) << 16);
    if (lane == 0) r[node] = rr + dd * dd;  // rowsum of Anorm at node
}

// ---------------- gemm: C[M,128] = A[M,128] @ Wf[128,128], bf16 IO ----------
// MFMA 16x16x32. In-place safe: each wave loads its 16 A-rows into regs
// before any store to the same rows (A/C intentionally NOT __restrict__).
__global__ __launch_bounds__(256) void gemm128b(const u16* A, const float* __restrict__ Bw,
                                                u16* C, int M) {
    __shared__ __align__(16) u16 Bt[128][136];  // B^T as bf16, +8 pad
    int tid = threadIdx.x;
    for (int idx = tid; idx < 128 * 128; idx += 256) {
        int k = idx >> 7, n = idx & 127;
        Bt[n][k] = f2bf(Bw[idx]);
    }
    __syncthreads();

    int wave = tid >> 6, lane = tid & 63;
    int quad = lane >> 4, mn = lane & 15;
    long row0 = (long)blockIdx.x * 64 + wave * 16;
    if (row0 >= M) return;

    bf16x8 afrag[4];  // A[m=row0+mn][k = kk*32 + quad*8 + j]
    const u16* Arow = A + (row0 + mn) * 128 + quad * 8;
#pragma unroll
    for (int kk = 0; kk < 4; ++kk)
        afrag[kk] = *reinterpret_cast<const bf16x8*>(Arow + kk * 32);

#pragma unroll
    for (int n0 = 0; n0 < 8; ++n0) {
        f32x4 acc = {0.f, 0.f, 0.f, 0.f};
#pragma unroll
        for (int kk = 0; kk < 4; ++kk) {
            bf16x8 bfrag =
                *reinterpret_cast<const bf16x8*>(&Bt[n0 * 16 + mn][kk * 32 + quad * 8]);
            acc = __builtin_amdgcn_mfma_f32_16x16x32_bf16(afrag[kk], bfrag, acc, 0, 0, 0);
        }
        int col = n0 * 16 + mn;  // C/D: col=lane&15(+16*n0), row=quad*4+reg
#pragma unroll
        for (int r = 0; r < 4; ++r)
            C[(row0 + quad * 4 + r) * 128 + col] = f2bf(acc[r]);
    }
}

// ---------------- gather2 + fused bias/rowsum-bias + reparam ----------------
// acc = Anorm@t + r_d*bb + bcat ; lanes 0..31 = mu cols, 32..63 = ls cols.
__global__ __launch_bounds__(256) void gather2(const u32* __restrict__ tb,
                                               const int* __restrict__ csr,
                                               const u32* __restrict__ rowstart,
                                               const float* __restrict__ dis,
                                               const float* __restrict__ r,
                                               const float* __restrict__ bb,
                                               const float* __restrict__ bcat,
                                               const float* __restrict__ eps,
                                               float* __restrict__ out, int N) {
    int node = (blockIdx.x * 256 + threadIdx.x) >> 6;
    if (node >= N) return;
    int lane = threadIdx.x & 63;
    float dd = dis[node];
    u32 beg = rowstart[node], end = rowstart[node + 1];
    u32 sv = tb[(long)node * 64 + lane];
    float accx = bflo(sv) * dd * dd, accy = bfhi(sv) * dd * dd;
    for (u32 e0 = beg; e0 < end; e0 += 64) {
        int s = 0; float ds = 0.f;
        if (e0 + (u32)lane < end) { s = csr[e0 + lane]; ds = dis[s]; }
        int cnt = (int)min(64u, end - e0);
#pragma unroll 4
        for (int j = 0; j < cnt; ++j) {
            int sj = __shfl(s, j);
            float nj = __shfl(ds, j) * dd;
            u32 w = tb[(long)sj * 64 + lane];
            accx += bflo(w) * nj;
            accy += bfhi(w) * nj;
        }
    }
    float rd = r[node];
    int c0 = 2 * lane;
    accx += rd * bb[c0] + bcat[c0];
    accy += rd * bb[c0 + 1] + bcat[c0 + 1];
    long NO = (long)N * 64;
    float ox = __shfl(accx, (lane + 32) & 63);  // matching ls for lane<32
    float oy = __shfl(accy, (lane + 32) & 63);
    if (lane < 32) {
        ((float2*)(out + NO))[(long)node * 32 + lane] = make_float2(accx, accy);  // mu
        float2 e2 = ((const float2*)eps)[(long)node * 32 + lane];
        float2 z = make_float2(accx + e2.x * __expf(ox), accy + e2.y * __expf(oy));
        ((float2*)out)[(long)node * 32 + lane] = z;                               // z
    } else {
        ((float2*)(out + 2 * NO))[(long)node * 32 + (lane - 32)] =
            make_float2(accx, accy);                                              // ls
    }
}

// ---------------------------------------------------------------------------
extern "C" void kernel_launch(void* const* d_in, const int* in_sizes, int n_in,
                              void* d_out, int out_size, void* d_ws, size_t ws_size,
                              hipStream_t stream) {
    const float* x   = (const float*)d_in[0];
    const int* ei    = (const int*)d_in[1];
    const float* W1  = (const float*)d_in[2];
    const float* b1  = (const float*)d_in[3];
    const float* Wmu = (const float*)d_in[4];
    const float* bmu = (const float*)d_in[5];
    const float* Wls = (const float*)d_in[6];
    const float* bls = (const float*)d_in[7];
    const float* eps = (const float*)d_in[8];
    float* out = (float*)d_out;

    const int N = in_sizes[0] / 128;   // 100000
    const int E = in_sizes[1] / 2;     // 1600000
    const int* src = ei;
    const int* dst = ei + E;
    const int NB = (N + 255) / 256;    // 391

    // WS layout (bytes), total ~65.7 MB:
    char* ws = (char*)d_ws;
    u32* deg       = (u32*)(ws + 0);         //   400,000
    u32* rowstart  = (u32*)(ws + 401408);    //   400,004
    u32* blockSums = (u32*)(ws + 802816);    //     2,048
    u32* blockOffs = (u32*)(ws + 804864);    //     2,048
    float* dis     = (float*)(ws + 806912);  //   400,000
    float* r       = (float*)(ws + 1207296); //   400,000
    float* Wf      = (float*)(ws + 1608704); //    65,536
    float* bb      = (float*)(ws + 1674240); //       512
    float* bcat    = (float*)(ws + 1674752); //       512
    u32* loc       = (u32*)(ws + 1675264);   // 6,400,000
    int* csr       = (int*)(ws + 8075264);   // 6,400,000
    u32* xb        = (u32*)(ws + 14475264);  // 25,600,000 (bf16 x)
    u32* bufA      = (u32*)(ws + 40075264);  // 25,600,000 (bf16 y -> t)

    hipMemsetAsync(deg, 0, (size_t)N * sizeof(u32), stream);

    int gridE = (E + 255) / 256;
    deg_hist<<<gridE, 256, 0, stream>>>(dst, deg, loc, E);
    scanA<<<NB, 256, 0, stream>>>(deg, blockSums, N);
    scanB<<<1, 512, 0, stream>>>(blockSums, blockOffs, NB);
    scanC<<<NB, 256, 0, stream>>>(deg, blockOffs, rowstart, dis, N, E);
    place_kernel<<<gridE, 256, 0, stream>>>(src, dst, loc, rowstart, csr, E);
    fuse_w<<<64, 256, 0, stream>>>(W1, Wmu, Wls, b1, bmu, bls, Wf, bb, bcat);

    long Q = (long)N * 128 / 4;
    convert_x<<<(int)((Q + 255) / 256), 256, 0, stream>>>(x, xb, Q);

    int gridG = (N * 64 + 255) / 256;  // 1 wave/node
    int gemmBlocks = (N + 63) / 64;

    gather1<<<gridG, 256, 0, stream>>>(xb, csr, rowstart, dis, bufA, r, N);
    gemm128b<<<gemmBlocks, 256, 0, stream>>>((const u16*)bufA, Wf, (u16*)bufA, N);
    gather2<<<gridG, 256, 0, stream>>>(bufA, csr, rowstart, dis, r, bb, bcat, eps,
                                       out, N);
}

// Round 6
// 505.490 us; speedup vs baseline: 5.7989x; 1.0275x over previous
//
#include <hip/hip_runtime.h>
#include <hip/hip_bf16.h>

// ---------------------------------------------------------------------------
// GraphEncoder (VGAE 2-layer GCN + reparam), fp32 in/out, edge_index int32.
// Round 6: gathers were latency-bound (134us @ 2.2TB/s, VALU 26%) ->
//  * 4 nodes/wave, 16 lanes/node, uint4 row loads (4 indep chains/wave)
//  * features prescaled by dis  => inner loop = pure sum (no per-edge norm)
//  * zero-row at index N => branch-free fully-unrolled 16-edge batches
//  * rowsum r via 1 f32 atomic/edge folded into place; CSR build vectorized.
// Math: [mu|ls] = Anorm@((Anorm@x)@Wf) + r(x)bb + bcat,  Wf=W1@[Wmu|Wls],
//       bb=b1@[Wmu|Wls], r_d = dis_d*(sum_{s in N(d)} dis_s + dis_d).
// ---------------------------------------------------------------------------

typedef unsigned int u32;
typedef unsigned short u16;
typedef __bf16 bf16x8 __attribute__((ext_vector_type(8)));
typedef float f32x4 __attribute__((ext_vector_type(4)));

__device__ __forceinline__ u16 f2bf(float f) {  // fp32 -> bf16 RNE
    union { float f; u32 u; } v; v.f = f;
    u32 u = v.u;
    u += 0x7fffu + ((u >> 16) & 1u);
    return (u16)(u >> 16);
}
__device__ __forceinline__ float bflo(u32 p) {
    union { u32 u; float f; } v; v.u = p << 16; return v.f;
}
__device__ __forceinline__ float bfhi(u32 p) {
    union { u32 u; float f; } v; v.u = p & 0xffff0000u; return v.f;
}

// ---------------- degree histogram + per-edge local offset (x4) -------------
__global__ __launch_bounds__(256) void deg_hist(const int* __restrict__ dst,
                                                u32* __restrict__ deg,
                                                u32* __restrict__ loc, int E) {
    int i4 = (blockIdx.x * 256 + threadIdx.x) * 4;
    if (i4 + 3 < E) {
        int4 d4 = *(const int4*)(dst + i4);
        uint4 l4;
        l4.x = atomicAdd(&deg[d4.x], 1u);
        l4.y = atomicAdd(&deg[d4.y], 1u);
        l4.z = atomicAdd(&deg[d4.z], 1u);
        l4.w = atomicAdd(&deg[d4.w], 1u);
        *(uint4*)(loc + i4) = l4;
    } else {
        for (int i = i4; i < E; ++i) loc[i] = atomicAdd(&deg[dst[i]], 1u);
    }
}

// ---------------- scan A: per-block totals ----------------
__global__ __launch_bounds__(256) void scanA(const u32* __restrict__ deg,
                                             u32* __restrict__ blockSums, int N) {
    __shared__ u32 s[256];
    int t = threadIdx.x, i = blockIdx.x * 256 + t;
    s[t] = (i < N) ? deg[i] : 0u;
    for (int off = 128; off > 0; off >>= 1) {
        __syncthreads();
        if (t < off) s[t] += s[t + off];
    }
    if (t == 0) blockSums[blockIdx.x] = s[0];
}

// ---------------- scan B: exclusive scan of block totals (1 block) ----------
__global__ __launch_bounds__(512) void scanB(const u32* __restrict__ blockSums,
                                             u32* __restrict__ blockOffs, int NB) {
    __shared__ u32 s[512];
    int t = threadIdx.x;
    u32 v = (t < NB) ? blockSums[t] : 0u;
    s[t] = v;
    for (int off = 1; off < 512; off <<= 1) {
        __syncthreads();
        u32 add = (t >= off) ? s[t - off] : 0u;
        __syncthreads();
        s[t] += add;
    }
    __syncthreads();
    if (t < NB) blockOffs[t] = s[t] - v;  // exclusive
}

// ---------------- scan C: rowstart + dis ----------------
__global__ __launch_bounds__(256) void scanC(const u32* __restrict__ deg,
                                             const u32* __restrict__ blockOffs,
                                             u32* __restrict__ rowstart,
                                             float* __restrict__ dis, int N, int E) {
    __shared__ u32 s[256];
    int t = threadIdx.x, i = blockIdx.x * 256 + t;
    u32 v = (i < N) ? deg[i] : 0u;
    s[t] = v;
    for (int off = 1; off < 256; off <<= 1) {
        __syncthreads();
        u32 add = (t >= off) ? s[t - off] : 0u;
        __syncthreads();
        s[t] += add;
    }
    __syncthreads();
    if (i < N) {
        rowstart[i] = blockOffs[blockIdx.x] + s[t] - v;  // exclusive
        dis[i] = rsqrtf((float)v + 1.0f);
    }
    if (i == 0) rowstart[N] = (u32)E;
}

// ---------------- CSR placement + rowsum scatter (x4, no u32 atomics) -------
__global__ __launch_bounds__(256) void place_kernel(const int* __restrict__ src,
                                                    const int* __restrict__ dst,
                                                    const u32* __restrict__ loc,
                                                    const u32* __restrict__ rowstart,
                                                    const float* __restrict__ dis,
                                                    int* __restrict__ csr,
                                                    float* __restrict__ r0, int E) {
    int i4 = (blockIdx.x * 256 + threadIdx.x) * 4;
    if (i4 + 3 < E) {
        int4 s4 = *(const int4*)(src + i4);
        int4 d4 = *(const int4*)(dst + i4);
        uint4 l4 = *(const uint4*)(loc + i4);
        csr[rowstart[d4.x] + l4.x] = s4.x;
        csr[rowstart[d4.y] + l4.y] = s4.y;
        csr[rowstart[d4.z] + l4.z] = s4.z;
        csr[rowstart[d4.w] + l4.w] = s4.w;
        unsafeAtomicAdd(&r0[d4.x], dis[s4.x]);
        unsafeAtomicAdd(&r0[d4.y], dis[s4.y]);
        unsafeAtomicAdd(&r0[d4.z], dis[s4.z]);
        unsafeAtomicAdd(&r0[d4.w], dis[s4.w]);
    } else {
        for (int i = i4; i < E; ++i) {
            csr[rowstart[dst[i]] + loc[i]] = src[i];
            unsafeAtomicAdd(&r0[dst[i]], dis[src[i]]);
        }
    }
}

// ---------------- fuse weights: Wf = W1@[Wmu|Wls], bb = b1@[Wmu|Wls] --------
__global__ __launch_bounds__(256) void fuse_w(const float* __restrict__ W1,
                                              const float* __restrict__ Wmu,
                                              const float* __restrict__ Wls,
                                              const float* __restrict__ b1,
                                              const float* __restrict__ bmu,
                                              const float* __restrict__ bls,
                                              float* __restrict__ Wf,
                                              float* __restrict__ bb,
                                              float* __restrict__ bcat) {
    int idx = blockIdx.x * 256 + threadIdx.x;  // 16384
    if (idx >= 16384) return;
    int k = idx >> 7, n = idx & 127;
    const float* Wcol = (n < 64) ? (Wmu + n) : (Wls + (n - 64));
    float acc = 0.f;
#pragma unroll 8
    for (int j = 0; j < 128; ++j) acc += W1[k * 128 + j] * Wcol[j * 64];
    Wf[idx] = acc;
    if (k == 0) {
        float accb = 0.f;
#pragma unroll 8
        for (int j = 0; j < 128; ++j) accb += b1[j] * Wcol[j * 64];
        bb[n] = accb;
        bcat[n] = (n < 64) ? bmu[n] : bls[n - 64];
    }
}

// ---------------- xs = bf16(x * dis[node]) ; zero row N in xs and bufA ------
__global__ __launch_bounds__(256) void convert_x(const float* __restrict__ x,
                                                 const float* __restrict__ dis,
                                                 u32* __restrict__ xs,
                                                 u32* __restrict__ bufA, int N) {
    long i = (long)blockIdx.x * 256 + threadIdx.x;  // (N+1)*32 threads
    long node = i >> 5;
    if (node > N) return;
    if (node == N) {  // zero row for branch-free dummy reads
        ((uint2*)xs)[i] = make_uint2(0u, 0u);
        ((uint2*)bufA)[i] = make_uint2(0u, 0u);
        return;
    }
    float dd = dis[node];
    f32x4 v = ((const f32x4*)x)[i];
    u32 p0 = (u32)f2bf(v[0] * dd) | ((u32)f2bf(v[1] * dd) << 16);
    u32 p1 = (u32)f2bf(v[2] * dd) | ((u32)f2bf(v[3] * dd) << 16);
    ((uint2*)xs)[i] = make_uint2(p0, p1);
}

// ---------------- gather1: yb[d] = bf16( dd * (xs[d] + sum_s xs[s]) ) -------
// 4 nodes/wave, 16 lanes/node, uint4 (8 bf16) per lane. Branch-free inner
// batch of 16 via zero-row (index N) dummies.
__global__ __launch_bounds__(256) void gather1(const u32* __restrict__ xs,
                                               const int* __restrict__ csr,
                                               const u32* __restrict__ rowstart,
                                               const float* __restrict__ dis,
                                               u32* __restrict__ yb, int N) {
    int wid = (blockIdx.x * 256 + threadIdx.x) >> 6;
    int sub = (threadIdx.x & 63) >> 4, l = threadIdx.x & 15;
    int node = wid * 4 + sub;
    bool live = node < N;
    int nodeC = live ? node : 0;
    float dd = dis[nodeC];
    u32 beg = live ? rowstart[nodeC] : 0u;
    u32 end = live ? rowstart[nodeC + 1] : 0u;
    const uint4* xs4 = (const uint4*)xs;

    uint4 selfv = xs4[(long)nodeC * 16 + l];  // acc init = xs[d] (self term)
    float acc0 = bflo(selfv.x), acc1 = bfhi(selfv.x);
    float acc2 = bflo(selfv.y), acc3 = bfhi(selfv.y);
    float acc4 = bflo(selfv.z), acc5 = bfhi(selfv.z);
    float acc6 = bflo(selfv.w), acc7 = bfhi(selfv.w);

    for (u32 e0 = beg; e0 < end; e0 += 16) {
        u32 cnt = min(16u, end - e0);
        int s = ((u32)l < cnt) ? csr[e0 + l] : N;  // dummy -> zero row
#pragma unroll 8
        for (int j = 0; j < 16; ++j) {
            int sj = __shfl(s, sub * 16 + j);
            uint4 w = xs4[(long)sj * 16 + l];
            acc0 += bflo(w.x); acc1 += bfhi(w.x);
            acc2 += bflo(w.y); acc3 += bfhi(w.y);
            acc4 += bflo(w.z); acc5 += bfhi(w.z);
            acc6 += bflo(w.w); acc7 += bfhi(w.w);
        }
    }
    if (live) {
        uint4 o;
        o.x = (u32)f2bf(acc0 * dd) | ((u32)f2bf(acc1 * dd) << 16);
        o.y = (u32)f2bf(acc2 * dd) | ((u32)f2bf(acc3 * dd) << 16);
        o.z = (u32)f2bf(acc4 * dd) | ((u32)f2bf(acc5 * dd) << 16);
        o.w = (u32)f2bf(acc6 * dd) | ((u32)f2bf(acc7 * dd) << 16);
        ((uint4*)yb)[(long)node * 16 + l] = o;
    }
}

// ---------------- gemm: C[M,128] = bf16( (A@Wf) * dis[row] )  (in-place) ----
__global__ __launch_bounds__(256) void gemm128b(const u16* A, const float* __restrict__ Bw,
                                                const float* __restrict__ dis,
                                                u16* C, int M) {
    __shared__ __align__(16) u16 Bt[128][136];  // Wf^T as bf16, +8 pad
    int tid = threadIdx.x;
    for (int idx = tid; idx < 128 * 128; idx += 256) {
        int k = idx >> 7, n = idx & 127;
        Bt[n][k] = f2bf(Bw[idx]);
    }
    __syncthreads();

    int wave = tid >> 6, lane = tid & 63;
    int quad = lane >> 4, mn = lane & 15;
    long row0 = (long)blockIdx.x * 64 + wave * 16;
    if (row0 >= M) return;

    bf16x8 afrag[4];  // A[m=row0+mn][k = kk*32 + quad*8 + j]
    const u16* Arow = A + (row0 + mn) * 128 + quad * 8;
#pragma unroll
    for (int kk = 0; kk < 4; ++kk)
        afrag[kk] = *reinterpret_cast<const bf16x8*>(Arow + kk * 32);

    float disr[4];  // C/D rows owned by this lane: row0 + quad*4 + r
#pragma unroll
    for (int r = 0; r < 4; ++r) disr[r] = dis[row0 + quad * 4 + r];

#pragma unroll
    for (int n0 = 0; n0 < 8; ++n0) {
        f32x4 acc = {0.f, 0.f, 0.f, 0.f};
#pragma unroll
        for (int kk = 0; kk < 4; ++kk) {
            bf16x8 bfrag =
                *reinterpret_cast<const bf16x8*>(&Bt[n0 * 16 + mn][kk * 32 + quad * 8]);
            acc = __builtin_amdgcn_mfma_f32_16x16x32_bf16(afrag[kk], bfrag, acc, 0, 0, 0);
        }
        int col = n0 * 16 + mn;  // C/D: col=lane&15(+16*n0), row=quad*4+reg
#pragma unroll
        for (int r = 0; r < 4; ++r)
            C[(row0 + quad * 4 + r) * 128 + col] = f2bf(acc[r] * disr[r]);
    }
}

// ---------------- gather2 + fused bias + reparam ----------------------------
// val = dd*(ts[d] + sum_s ts[s]) + r_d*bb + bcat ; cols 0..63 mu, 64..127 ls.
__global__ __launch_bounds__(256) void gather2(const u32* __restrict__ ts,
                                               const int* __restrict__ csr,
                                               const u32* __restrict__ rowstart,
                                               const float* __restrict__ dis,
                                               const float* __restrict__ r0,
                                               const float* __restrict__ bb,
                                               const float* __restrict__ bcat,
                                               const float* __restrict__ eps,
                                               float* __restrict__ out, int N) {
    int wid = (blockIdx.x * 256 + threadIdx.x) >> 6;
    int sub = (threadIdx.x & 63) >> 4, l = threadIdx.x & 15;
    int node = wid * 4 + sub;
    bool live = node < N;
    int nodeC = live ? node : 0;
    float dd = dis[nodeC];
    u32 beg = live ? rowstart[nodeC] : 0u;
    u32 end = live ? rowstart[nodeC + 1] : 0u;
    const uint4* ts4 = (const uint4*)ts;

    uint4 selfv = ts4[(long)nodeC * 16 + l];
    float a0 = bflo(selfv.x), a1 = bfhi(selfv.x);
    float a2 = bflo(selfv.y), a3 = bfhi(selfv.y);
    float a4 = bflo(selfv.z), a5 = bfhi(selfv.z);
    float a6 = bflo(selfv.w), a7 = bfhi(selfv.w);

    for (u32 e0 = beg; e0 < end; e0 += 16) {
        u32 cnt = min(16u, end - e0);
        int s = ((u32)l < cnt) ? csr[e0 + l] : N;
#pragma unroll 8
        for (int j = 0; j < 16; ++j) {
            int sj = __shfl(s, sub * 16 + j);
            uint4 w = ts4[(long)sj * 16 + l];
            a0 += bflo(w.x); a1 += bfhi(w.x);
            a2 += bflo(w.y); a3 += bfhi(w.y);
            a4 += bflo(w.z); a5 += bfhi(w.z);
            a6 += bflo(w.w); a7 += bfhi(w.w);
        }
    }

    float rd = dd * (r0[nodeC] + dd);
    int c0 = l * 8;  // cols c0..c0+7 (l<8: mu cols c0; l>=8: ls cols c0-64)
    f32x4 blo = ((const f32x4*)bb)[2 * l], bhi = ((const f32x4*)bb)[2 * l + 1];
    f32x4 clo = ((const f32x4*)bcat)[2 * l], chi = ((const f32x4*)bcat)[2 * l + 1];
    float v0 = a0 * dd + rd * blo[0] + clo[0];
    float v1 = a1 * dd + rd * blo[1] + clo[1];
    float v2 = a2 * dd + rd * blo[2] + clo[2];
    float v3 = a3 * dd + rd * blo[3] + clo[3];
    float v4 = a4 * dd + rd * bhi[0] + chi[0];
    float v5 = a5 * dd + rd * bhi[1] + chi[1];
    float v6 = a6 * dd + rd * bhi[2] + chi[2];
    float v7 = a7 * dd + rd * bhi[3] + chi[3];

    // ls values live 8 lanes up within the wave (same subgroup, l+8).
    int src = (threadIdx.x & 63) + 8;
    float w0 = __shfl(v0, src), w1 = __shfl(v1, src), w2 = __shfl(v2, src),
          w3 = __shfl(v3, src), w4 = __shfl(v4, src), w5 = __shfl(v5, src),
          w6 = __shfl(v6, src), w7 = __shfl(v7, src);

    if (!live) return;
    long NO = (long)N * 64;
    if (l < 8) {  // mu cols c0..c0+7 ; also compute z
        float* mu = out + NO + (long)node * 64 + c0;
        ((f32x4*)mu)[0] = f32x4{v0, v1, v2, v3};
        ((f32x4*)mu)[1] = f32x4{v4, v5, v6, v7};
        const float* ep = eps + (long)node * 64 + c0;
        f32x4 e0v = ((const f32x4*)ep)[0], e1v = ((const f32x4*)ep)[1];
        float* z = out + (long)node * 64 + c0;
        ((f32x4*)z)[0] = f32x4{v0 + e0v[0] * __expf(w0), v1 + e0v[1] * __expf(w1),
                               v2 + e0v[2] * __expf(w2), v3 + e0v[3] * __expf(w3)};
        ((f32x4*)z)[1] = f32x4{v4 + e1v[0] * __expf(w4), v5 + e1v[1] * __expf(w5),
                               v6 + e1v[2] * __expf(w6), v7 + e1v[3] * __expf(w7)};
    } else {      // logstd cols (c0-64)..(c0-64+7)
        float* ls = out + 2 * NO + (long)node * 64 + (c0 - 64);
        ((f32x4*)ls)[0] = f32x4{v0, v1, v2, v3};
        ((f32x4*)ls)[1] = f32x4{v4, v5, v6, v7};
    }
}

// ---------------------------------------------------------------------------
extern "C" void kernel_launch(void* const* d_in, const int* in_sizes, int n_in,
                              void* d_out, int out_size, void* d_ws, size_t ws_size,
                              hipStream_t stream) {
    const float* x   = (const float*)d_in[0];
    const int* ei    = (const int*)d_in[1];
    const float* W1  = (const float*)d_in[2];
    const float* b1  = (const float*)d_in[3];
    const float* Wmu = (const float*)d_in[4];
    const float* bmu = (const float*)d_in[5];
    const float* Wls = (const float*)d_in[6];
    const float* bls = (const float*)d_in[7];
    const float* eps = (const float*)d_in[8];
    float* out = (float*)d_out;

    const int N = in_sizes[0] / 128;   // 100000
    const int E = in_sizes[1] / 2;     // 1600000
    const int* src = ei;
    const int* dst = ei + E;
    const int NB = (N + 255) / 256;    // 391

    // WS layout (bytes), total ~66 MB. deg & r0 adjacent -> one memset.
    char* ws = (char*)d_ws;
    u32* deg       = (u32*)(ws + 0);         //   400,000
    float* r0      = (float*)(ws + 400000);  //   400,000   (memset with deg)
    u32* rowstart  = (u32*)(ws + 802816);    //   400,004
    u32* blockSums = (u32*)(ws + 1204224);   //     2,048
    u32* blockOffs = (u32*)(ws + 1206272);   //     2,048
    float* dis     = (float*)(ws + 1208320); //   400,000
    float* Wf      = (float*)(ws + 1610752); //    65,536
    float* bb      = (float*)(ws + 1676288); //       512
    float* bcat    = (float*)(ws + 1676800); //       512
    u32* loc       = (u32*)(ws + 1677312);   // 6,400,000
    int* csr       = (int*)(ws + 8077312);   // 6,400,000
    u32* xs        = (u32*)(ws + 14477312);  // 25,600,256 ((N+1) rows bf16)
    u32* bufA      = (u32*)(ws + 40077568);  // 25,600,256 ((N+1) rows bf16)

    hipMemsetAsync(deg, 0, 800000, stream);  // deg + r0

    int gridE4 = (E / 4 + 255) / 256;
    deg_hist<<<gridE4, 256, 0, stream>>>(dst, deg, loc, E);
    scanA<<<NB, 256, 0, stream>>>(deg, blockSums, N);
    scanB<<<1, 512, 0, stream>>>(blockSums, blockOffs, NB);
    scanC<<<NB, 256, 0, stream>>>(deg, blockOffs, rowstart, dis, N, E);
    place_kernel<<<gridE4, 256, 0, stream>>>(src, dst, loc, rowstart, dis, csr, r0, E);
    fuse_w<<<64, 256, 0, stream>>>(W1, Wmu, Wls, b1, bmu, bls, Wf, bb, bcat);

    long Qc = (long)(N + 1) * 32;  // uint2-granular threads incl. zero row
    convert_x<<<(int)((Qc + 255) / 256), 256, 0, stream>>>(x, dis, xs, bufA, N);

    int gridG = ((N + 3) / 4 * 64 + 255) / 256;  // 1 wave / 4 nodes
    int gemmBlocks = (N + 63) / 64;

    gather1<<<gridG, 256, 0, stream>>>(xs, csr, rowstart, dis, bufA, N);
    gemm128b<<<gemmBlocks, 256, 0, stream>>>((const u16*)bufA, Wf, dis, (u16*)bufA, N);
    gather2<<<gridG, 256, 0, stream>>>(bufA, csr, rowstart, dis, r0, bb, bcat, eps,
                                       out, N);
}

// Round 7
// 451.535 us; speedup vs baseline: 6.4918x; 1.1195x over previous
//
#include <hip/hip_runtime.h>
#include <hip/hip_bf16.h>

// ---------------------------------------------------------------------------
// GraphEncoder (VGAE 2-layer GCN + reparam), fp32 in/out, edge_index int32.
// Round 7: r0 rowsum atomics eliminated via identity
//   Anorm@(g + 1(x)bb) = Anorm@g + r(x)bb
// -> bb folded into GEMM epilogue; place_kernel = pure scattered store.
// Math: ts = ((Anorm@x)@Wf + 1(x)bb)*dis ; [mu|ls] = dd*(ts[d]+sum ts[s])+bcat
//       Wf = W1@[Wmu|Wls], bb = b1@[Wmu|Wls].
// Features bf16 prescaled by dis; f32 accumulation everywhere.
// ---------------------------------------------------------------------------

typedef unsigned int u32;
typedef unsigned short u16;
typedef __bf16 bf16x8 __attribute__((ext_vector_type(8)));
typedef float f32x4 __attribute__((ext_vector_type(4)));

__device__ __forceinline__ u16 f2bf(float f) {  // fp32 -> bf16 RNE
    union { float f; u32 u; } v; v.f = f;
    u32 u = v.u;
    u += 0x7fffu + ((u >> 16) & 1u);
    return (u16)(u >> 16);
}
__device__ __forceinline__ float bflo(u32 p) {
    union { u32 u; float f; } v; v.u = p << 16; return v.f;
}
__device__ __forceinline__ float bfhi(u32 p) {
    union { u32 u; float f; } v; v.u = p & 0xffff0000u; return v.f;
}

// ---------------- degree histogram + per-edge local offset (x4) -------------
__global__ __launch_bounds__(256) void deg_hist(const int* __restrict__ dst,
                                                u32* __restrict__ deg,
                                                u32* __restrict__ loc, int E) {
    int i4 = (blockIdx.x * 256 + threadIdx.x) * 4;
    if (i4 + 3 < E) {
        int4 d4 = *(const int4*)(dst + i4);
        uint4 l4;
        l4.x = atomicAdd(&deg[d4.x], 1u);
        l4.y = atomicAdd(&deg[d4.y], 1u);
        l4.z = atomicAdd(&deg[d4.z], 1u);
        l4.w = atomicAdd(&deg[d4.w], 1u);
        *(uint4*)(loc + i4) = l4;
    } else {
        for (int i = i4; i < E; ++i) loc[i] = atomicAdd(&deg[dst[i]], 1u);
    }
}

// ---------------- scan A: per-block totals ----------------
__global__ __launch_bounds__(256) void scanA(const u32* __restrict__ deg,
                                             u32* __restrict__ blockSums, int N) {
    __shared__ u32 s[256];
    int t = threadIdx.x, i = blockIdx.x * 256 + t;
    s[t] = (i < N) ? deg[i] : 0u;
    for (int off = 128; off > 0; off >>= 1) {
        __syncthreads();
        if (t < off) s[t] += s[t + off];
    }
    if (t == 0) blockSums[blockIdx.x] = s[0];
}

// ---------------- scan B: exclusive scan of block totals (1 block) ----------
__global__ __launch_bounds__(512) void scanB(const u32* __restrict__ blockSums,
                                             u32* __restrict__ blockOffs, int NB) {
    __shared__ u32 s[512];
    int t = threadIdx.x;
    u32 v = (t < NB) ? blockSums[t] : 0u;
    s[t] = v;
    for (int off = 1; off < 512; off <<= 1) {
        __syncthreads();
        u32 add = (t >= off) ? s[t - off] : 0u;
        __syncthreads();
        s[t] += add;
    }
    __syncthreads();
    if (t < NB) blockOffs[t] = s[t] - v;  // exclusive
}

// ---------------- scan C: rowstart + dis ----------------
__global__ __launch_bounds__(256) void scanC(const u32* __restrict__ deg,
                                             const u32* __restrict__ blockOffs,
                                             u32* __restrict__ rowstart,
                                             float* __restrict__ dis, int N, int E) {
    __shared__ u32 s[256];
    int t = threadIdx.x, i = blockIdx.x * 256 + t;
    u32 v = (i < N) ? deg[i] : 0u;
    s[t] = v;
    for (int off = 1; off < 256; off <<= 1) {
        __syncthreads();
        u32 add = (t >= off) ? s[t - off] : 0u;
        __syncthreads();
        s[t] += add;
    }
    __syncthreads();
    if (i < N) {
        rowstart[i] = blockOffs[blockIdx.x] + s[t] - v;  // exclusive
        dis[i] = rsqrtf((float)v + 1.0f);
    }
    if (i == 0) rowstart[N] = (u32)E;
}

// ---------------- CSR placement (x4, pure scattered store) ------------------
__global__ __launch_bounds__(256) void place_kernel(const int* __restrict__ src,
                                                    const int* __restrict__ dst,
                                                    const u32* __restrict__ loc,
                                                    const u32* __restrict__ rowstart,
                                                    int* __restrict__ csr, int E) {
    int i4 = (blockIdx.x * 256 + threadIdx.x) * 4;
    if (i4 + 3 < E) {
        int4 s4 = *(const int4*)(src + i4);
        int4 d4 = *(const int4*)(dst + i4);
        uint4 l4 = *(const uint4*)(loc + i4);
        csr[rowstart[d4.x] + l4.x] = s4.x;
        csr[rowstart[d4.y] + l4.y] = s4.y;
        csr[rowstart[d4.z] + l4.z] = s4.z;
        csr[rowstart[d4.w] + l4.w] = s4.w;
    } else {
        for (int i = i4; i < E; ++i) csr[rowstart[dst[i]] + loc[i]] = src[i];
    }
}

// ---------------- fuse weights: Wf = W1@[Wmu|Wls], bb = b1@[Wmu|Wls] --------
__global__ __launch_bounds__(256) void fuse_w(const float* __restrict__ W1,
                                              const float* __restrict__ Wmu,
                                              const float* __restrict__ Wls,
                                              const float* __restrict__ b1,
                                              const float* __restrict__ bmu,
                                              const float* __restrict__ bls,
                                              float* __restrict__ Wf,
                                              float* __restrict__ bb,
                                              float* __restrict__ bcat) {
    int idx = blockIdx.x * 256 + threadIdx.x;  // 16384
    if (idx >= 16384) return;
    int k = idx >> 7, n = idx & 127;
    const float* Wcol = (n < 64) ? (Wmu + n) : (Wls + (n - 64));
    float acc = 0.f;
#pragma unroll 8
    for (int j = 0; j < 128; ++j) acc += W1[k * 128 + j] * Wcol[j * 64];
    Wf[idx] = acc;
    if (k == 0) {
        float accb = 0.f;
#pragma unroll 8
        for (int j = 0; j < 128; ++j) accb += b1[j] * Wcol[j * 64];
        bb[n] = accb;
        bcat[n] = (n < 64) ? bmu[n] : bls[n - 64];
    }
}

// ---------------- xs = bf16(x * dis[node]) ; zero row N in xs and bufA ------
__global__ __launch_bounds__(256) void convert_x(const float* __restrict__ x,
                                                 const float* __restrict__ dis,
                                                 u32* __restrict__ xs,
                                                 u32* __restrict__ bufA, int N) {
    long i = (long)blockIdx.x * 256 + threadIdx.x;  // (N+1)*32 threads
    long node = i >> 5;
    if (node > N) return;
    if (node == N) {  // zero row for branch-free dummy reads
        ((uint2*)xs)[i] = make_uint2(0u, 0u);
        ((uint2*)bufA)[i] = make_uint2(0u, 0u);
        return;
    }
    float dd = dis[node];
    f32x4 v = ((const f32x4*)x)[i];
    u32 p0 = (u32)f2bf(v[0] * dd) | ((u32)f2bf(v[1] * dd) << 16);
    u32 p1 = (u32)f2bf(v[2] * dd) | ((u32)f2bf(v[3] * dd) << 16);
    ((uint2*)xs)[i] = make_uint2(p0, p1);
}

// ---------------- gather1: yb[d] = bf16( dd * (xs[d] + sum_s xs[s]) ) -------
// 4 nodes/wave, 16 lanes/node, uint4 (8 bf16) per lane. Branch-free inner
// batch of 16 via zero-row (index N) dummies.
__global__ __launch_bounds__(256) void gather1(const u32* __restrict__ xs,
                                               const int* __restrict__ csr,
                                               const u32* __restrict__ rowstart,
                                               const float* __restrict__ dis,
                                               u32* __restrict__ yb, int N) {
    int wid = (blockIdx.x * 256 + threadIdx.x) >> 6;
    int sub = (threadIdx.x & 63) >> 4, l = threadIdx.x & 15;
    int node = wid * 4 + sub;
    bool live = node < N;
    int nodeC = live ? node : 0;
    float dd = dis[nodeC];
    u32 beg = live ? rowstart[nodeC] : 0u;
    u32 end = live ? rowstart[nodeC + 1] : 0u;
    const uint4* xs4 = (const uint4*)xs;

    uint4 selfv = xs4[(long)nodeC * 16 + l];  // acc init = xs[d] (self term)
    float acc0 = bflo(selfv.x), acc1 = bfhi(selfv.x);
    float acc2 = bflo(selfv.y), acc3 = bfhi(selfv.y);
    float acc4 = bflo(selfv.z), acc5 = bfhi(selfv.z);
    float acc6 = bflo(selfv.w), acc7 = bfhi(selfv.w);

    for (u32 e0 = beg; e0 < end; e0 += 16) {
        u32 cnt = min(16u, end - e0);
        int s = ((u32)l < cnt) ? csr[e0 + l] : N;  // dummy -> zero row
#pragma unroll 8
        for (int j = 0; j < 16; ++j) {
            int sj = __shfl(s, sub * 16 + j);
            uint4 w = xs4[(long)sj * 16 + l];
            acc0 += bflo(w.x); acc1 += bfhi(w.x);
            acc2 += bflo(w.y); acc3 += bfhi(w.y);
            acc4 += bflo(w.z); acc5 += bfhi(w.z);
            acc6 += bflo(w.w); acc7 += bfhi(w.w);
        }
    }
    if (live) {
        uint4 o;
        o.x = (u32)f2bf(acc0 * dd) | ((u32)f2bf(acc1 * dd) << 16);
        o.y = (u32)f2bf(acc2 * dd) | ((u32)f2bf(acc3 * dd) << 16);
        o.z = (u32)f2bf(acc4 * dd) | ((u32)f2bf(acc5 * dd) << 16);
        o.w = (u32)f2bf(acc6 * dd) | ((u32)f2bf(acc7 * dd) << 16);
        ((uint4*)yb)[(long)node * 16 + l] = o;
    }
}

// ---------------- gemm: C = bf16( (A@Wf + 1(x)bb) * dis[row] ) (in-place) ---
// MFMA 16x16x32; the bb-add implements the r(x)bb rowsum-bias identity.
__global__ __launch_bounds__(256) void gemm128b(const u16* A, const float* __restrict__ Bw,
                                                const float* __restrict__ bb,
                                                const float* __restrict__ dis,
                                                u16* C, int M) {
    __shared__ __align__(16) u16 Bt[128][136];  // Wf^T as bf16, +8 pad
    __shared__ float bbS[128];
    int tid = threadIdx.x;
    for (int idx = tid; idx < 128 * 128; idx += 256) {
        int k = idx >> 7, n = idx & 127;
        Bt[n][k] = f2bf(Bw[idx]);
    }
    if (tid < 128) bbS[tid] = bb[tid];
    __syncthreads();

    int wave = tid >> 6, lane = tid & 63;
    int quad = lane >> 4, mn = lane & 15;
    long row0 = (long)blockIdx.x * 64 + wave * 16;
    if (row0 >= M) return;

    bf16x8 afrag[4];  // A[m=row0+mn][k = kk*32 + quad*8 + j]
    const u16* Arow = A + (row0 + mn) * 128 + quad * 8;
#pragma unroll
    for (int kk = 0; kk < 4; ++kk)
        afrag[kk] = *reinterpret_cast<const bf16x8*>(Arow + kk * 32);

    float disr[4];  // C/D rows owned by this lane: row0 + quad*4 + r
#pragma unroll
    for (int r = 0; r < 4; ++r) disr[r] = dis[row0 + quad * 4 + r];

#pragma unroll
    for (int n0 = 0; n0 < 8; ++n0) {
        f32x4 acc = {0.f, 0.f, 0.f, 0.f};
#pragma unroll
        for (int kk = 0; kk < 4; ++kk) {
            bf16x8 bfrag =
                *reinterpret_cast<const bf16x8*>(&Bt[n0 * 16 + mn][kk * 32 + quad * 8]);
            acc = __builtin_amdgcn_mfma_f32_16x16x32_bf16(afrag[kk], bfrag, acc, 0, 0, 0);
        }
        int col = n0 * 16 + mn;  // C/D: col=lane&15(+16*n0), row=quad*4+reg
#pragma unroll
        for (int r = 0; r < 4; ++r)
            C[(row0 + quad * 4 + r) * 128 + col] = f2bf((acc[r] + bbS[col]) * disr[r]);
    }
}

// ---------------- gather2 + bcat + reparam ----------------------------------
// val = dd*(ts[d] + sum_s ts[s]) + bcat ; cols 0..63 mu, 64..127 ls.
__global__ __launch_bounds__(256) void gather2(const u32* __restrict__ ts,
                                               const int* __restrict__ csr,
                                               const u32* __restrict__ rowstart,
                                               const float* __restrict__ dis,
                                               const float* __restrict__ bcat,
                                               const float* __restrict__ eps,
                                               float* __restrict__ out, int N) {
    int wid = (blockIdx.x * 256 + threadIdx.x) >> 6;
    int sub = (threadIdx.x & 63) >> 4, l = threadIdx.x & 15;
    int node = wid * 4 + sub;
    bool live = node < N;
    int nodeC = live ? node : 0;
    float dd = dis[nodeC];
    u32 beg = live ? rowstart[nodeC] : 0u;
    u32 end = live ? rowstart[nodeC + 1] : 0u;
    const uint4* ts4 = (const uint4*)ts;

    uint4 selfv = ts4[(long)nodeC * 16 + l];
    float a0 = bflo(selfv.x), a1 = bfhi(selfv.x);
    float a2 = bflo(selfv.y), a3 = bfhi(selfv.y);
    float a4 = bflo(selfv.z), a5 = bfhi(selfv.z);
    float a6 = bflo(selfv.w), a7 = bfhi(selfv.w);

    for (u32 e0 = beg; e0 < end; e0 += 16) {
        u32 cnt = min(16u, end - e0);
        int s = ((u32)l < cnt) ? csr[e0 + l] : N;
#pragma unroll 8
        for (int j = 0; j < 16; ++j) {
            int sj = __shfl(s, sub * 16 + j);
            uint4 w = ts4[(long)sj * 16 + l];
            a0 += bflo(w.x); a1 += bfhi(w.x);
            a2 += bflo(w.y); a3 += bfhi(w.y);
            a4 += bflo(w.z); a5 += bfhi(w.z);
            a6 += bflo(w.w); a7 += bfhi(w.w);
        }
    }

    int c0 = l * 8;  // cols c0..c0+7 (l<8: mu cols c0; l>=8: ls cols c0-64)
    f32x4 clo = ((const f32x4*)bcat)[2 * l], chi = ((const f32x4*)bcat)[2 * l + 1];
    float v0 = a0 * dd + clo[0];
    float v1 = a1 * dd + clo[1];
    float v2 = a2 * dd + clo[2];
    float v3 = a3 * dd + clo[3];
    float v4 = a4 * dd + chi[0];
    float v5 = a5 * dd + chi[1];
    float v6 = a6 * dd + chi[2];
    float v7 = a7 * dd + chi[3];

    // ls values live 8 lanes up within the wave (same subgroup, l+8).
    int srcl = (threadIdx.x & 63) + 8;
    float w0 = __shfl(v0, srcl), w1 = __shfl(v1, srcl), w2 = __shfl(v2, srcl),
          w3 = __shfl(v3, srcl), w4 = __shfl(v4, srcl), w5 = __shfl(v5, srcl),
          w6 = __shfl(v6, srcl), w7 = __shfl(v7, srcl);

    if (!live) return;
    long NO = (long)N * 64;
    if (l < 8) {  // mu cols c0..c0+7 ; also compute z
        float* mu = out + NO + (long)node * 64 + c0;
        ((f32x4*)mu)[0] = f32x4{v0, v1, v2, v3};
        ((f32x4*)mu)[1] = f32x4{v4, v5, v6, v7};
        const float* ep = eps + (long)node * 64 + c0;
        f32x4 e0v = ((const f32x4*)ep)[0], e1v = ((const f32x4*)ep)[1];
        float* z = out + (long)node * 64 + c0;
        ((f32x4*)z)[0] = f32x4{v0 + e0v[0] * __expf(w0), v1 + e0v[1] * __expf(w1),
                               v2 + e0v[2] * __expf(w2), v3 + e0v[3] * __expf(w3)};
        ((f32x4*)z)[1] = f32x4{v4 + e1v[0] * __expf(w4), v5 + e1v[1] * __expf(w5),
                               v6 + e1v[2] * __expf(w6), v7 + e1v[3] * __expf(w7)};
    } else {      // logstd cols (c0-64)..(c0-64+7)
        float* ls = out + 2 * NO + (long)node * 64 + (c0 - 64);
        ((f32x4*)ls)[0] = f32x4{v0, v1, v2, v3};
        ((f32x4*)ls)[1] = f32x4{v4, v5, v6, v7};
    }
}

// ---------------------------------------------------------------------------
extern "C" void kernel_launch(void* const* d_in, const int* in_sizes, int n_in,
                              void* d_out, int out_size, void* d_ws, size_t ws_size,
                              hipStream_t stream) {
    const float* x   = (const float*)d_in[0];
    const int* ei    = (const int*)d_in[1];
    const float* W1  = (const float*)d_in[2];
    const float* b1  = (const float*)d_in[3];
    const float* Wmu = (const float*)d_in[4];
    const float* bmu = (const float*)d_in[5];
    const float* Wls = (const float*)d_in[6];
    const float* bls = (const float*)d_in[7];
    const float* eps = (const float*)d_in[8];
    float* out = (float*)d_out;

    const int N = in_sizes[0] / 128;   // 100000
    const int E = in_sizes[1] / 2;     // 1600000
    const int* src = ei;
    const int* dst = ei + E;
    const int NB = (N + 255) / 256;    // 391

    // WS layout (bytes), total ~65 MB.
    char* ws = (char*)d_ws;
    u32* deg       = (u32*)(ws + 0);         //   400,000
    u32* rowstart  = (u32*)(ws + 401408);    //   400,004
    u32* blockSums = (u32*)(ws + 802816);    //     2,048
    u32* blockOffs = (u32*)(ws + 804864);    //     2,048
    float* dis     = (float*)(ws + 806912);  //   400,000
    float* Wf      = (float*)(ws + 1208320); //    65,536
    float* bb      = (float*)(ws + 1273856); //       512
    float* bcat    = (float*)(ws + 1274368); //       512
    u32* loc       = (u32*)(ws + 1274880);   // 6,400,000
    int* csr       = (int*)(ws + 7674880);   // 6,400,000
    u32* xs        = (u32*)(ws + 14074880);  // 25,600,256 ((N+1) rows bf16)
    u32* bufA      = (u32*)(ws + 39675136);  // 25,600,256 ((N+1) rows bf16)

    hipMemsetAsync(deg, 0, 400000, stream);

    int gridE4 = (E / 4 + 255) / 256;
    deg_hist<<<gridE4, 256, 0, stream>>>(dst, deg, loc, E);
    scanA<<<NB, 256, 0, stream>>>(deg, blockSums, N);
    scanB<<<1, 512, 0, stream>>>(blockSums, blockOffs, NB);
    scanC<<<NB, 256, 0, stream>>>(deg, blockOffs, rowstart, dis, N, E);
    place_kernel<<<gridE4, 256, 0, stream>>>(src, dst, loc, rowstart, csr, E);
    fuse_w<<<64, 256, 0, stream>>>(W1, Wmu, Wls, b1, bmu, bls, Wf, bb, bcat);

    long Qc = (long)(N + 1) * 32;  // uint2-granular threads incl. zero row
    convert_x<<<(int)((Qc + 255) / 256), 256, 0, stream>>>(x, dis, xs, bufA, N);

    int gridG = ((N + 3) / 4 * 64 + 255) / 256;  // 1 wave / 4 nodes
    int gemmBlocks = (N + 63) / 64;

    gather1<<<gridG, 256, 0, stream>>>(xs, csr, rowstart, dis, bufA, N);
    gemm128b<<<gemmBlocks, 256, 0, stream>>>((const u16*)bufA, Wf, bb, dis,
                                             (u16*)bufA, N);
    gather2<<<gridG, 256, 0, stream>>>(bufA, csr, rowstart, dis, bcat, eps, out, N);
}

// Round 8
// 425.822 us; speedup vs baseline: 6.8838x; 1.0604x over previous
//
#include <hip/hip_runtime.h>
#include <hip/hip_bf16.h>

// ---------------------------------------------------------------------------
// GraphEncoder (VGAE 2-layer GCN + reparam), fp32 in/out, edge_index int32.
// Round 8:
//  * gathers: explicit 8-deep uint4 load staging + csr batch prefetch (MLP)
//  * GEMM fused into gather1 (16-node LDS tile -> MFMA, WfT bf16 from L1)
//  * u8 loc in CSR build
// Math: ts = ((Anorm@x)@Wf + 1(x)bb)*dis ; [mu|ls] = dd*(ts[d]+sum ts[s])+bcat
//       Wf = W1@[Wmu|Wls], bb = b1@[Wmu|Wls]  (rowsum-bias identity).
// ---------------------------------------------------------------------------

typedef unsigned int u32;
typedef unsigned short u16;
typedef unsigned char u8;
typedef __bf16 bf16x8 __attribute__((ext_vector_type(8)));
typedef float f32x4 __attribute__((ext_vector_type(4)));

__device__ __forceinline__ u16 f2bf(float f) {  // fp32 -> bf16 RNE
    union { float f; u32 u; } v; v.f = f;
    u32 u = v.u;
    u += 0x7fffu + ((u >> 16) & 1u);
    return (u16)(u >> 16);
}
__device__ __forceinline__ float bflo(u32 p) {
    union { u32 u; float f; } v; v.u = p << 16; return v.f;
}
__device__ __forceinline__ float bfhi(u32 p) {
    union { u32 u; float f; } v; v.u = p & 0xffff0000u; return v.f;
}

// ---------------- degree histogram + per-edge u8 local offset (x4) ----------
__global__ __launch_bounds__(256) void deg_hist(const int* __restrict__ dst,
                                                u32* __restrict__ deg,
                                                u8* __restrict__ loc, int E) {
    int i4 = (blockIdx.x * 256 + threadIdx.x) * 4;
    if (i4 + 3 < E) {
        int4 d4 = *(const int4*)(dst + i4);
        uchar4 l4;
        l4.x = (u8)atomicAdd(&deg[d4.x], 1u);
        l4.y = (u8)atomicAdd(&deg[d4.y], 1u);
        l4.z = (u8)atomicAdd(&deg[d4.z], 1u);
        l4.w = (u8)atomicAdd(&deg[d4.w], 1u);
        *(uchar4*)(loc + i4) = l4;
    } else {
        for (int i = i4; i < E; ++i) loc[i] = (u8)atomicAdd(&deg[dst[i]], 1u);
    }
}

// ---------------- scan A: per-block totals ----------------
__global__ __launch_bounds__(256) void scanA(const u32* __restrict__ deg,
                                             u32* __restrict__ blockSums, int N) {
    __shared__ u32 s[256];
    int t = threadIdx.x, i = blockIdx.x * 256 + t;
    s[t] = (i < N) ? deg[i] : 0u;
    for (int off = 128; off > 0; off >>= 1) {
        __syncthreads();
        if (t < off) s[t] += s[t + off];
    }
    if (t == 0) blockSums[blockIdx.x] = s[0];
}

// ---------------- scan B: exclusive scan of block totals (1 block) ----------
__global__ __launch_bounds__(512) void scanB(const u32* __restrict__ blockSums,
                                             u32* __restrict__ blockOffs, int NB) {
    __shared__ u32 s[512];
    int t = threadIdx.x;
    u32 v = (t < NB) ? blockSums[t] : 0u;
    s[t] = v;
    for (int off = 1; off < 512; off <<= 1) {
        __syncthreads();
        u32 add = (t >= off) ? s[t - off] : 0u;
        __syncthreads();
        s[t] += add;
    }
    __syncthreads();
    if (t < NB) blockOffs[t] = s[t] - v;  // exclusive
}

// ---------------- scan C: rowstart + dis ----------------
__global__ __launch_bounds__(256) void scanC(const u32* __restrict__ deg,
                                             const u32* __restrict__ blockOffs,
                                             u32* __restrict__ rowstart,
                                             float* __restrict__ dis, int N, int E) {
    __shared__ u32 s[256];
    int t = threadIdx.x, i = blockIdx.x * 256 + t;
    u32 v = (i < N) ? deg[i] : 0u;
    s[t] = v;
    for (int off = 1; off < 256; off <<= 1) {
        __syncthreads();
        u32 add = (t >= off) ? s[t - off] : 0u;
        __syncthreads();
        s[t] += add;
    }
    __syncthreads();
    if (i < N) {
        rowstart[i] = blockOffs[blockIdx.x] + s[t] - v;  // exclusive
        dis[i] = rsqrtf((float)v + 1.0f);
    }
    if (i == 0) rowstart[N] = (u32)E;
}

// ---------------- CSR placement (x4, pure scattered store) ------------------
__global__ __launch_bounds__(256) void place_kernel(const int* __restrict__ src,
                                                    const int* __restrict__ dst,
                                                    const u8* __restrict__ loc,
                                                    const u32* __restrict__ rowstart,
                                                    int* __restrict__ csr, int E) {
    int i4 = (blockIdx.x * 256 + threadIdx.x) * 4;
    if (i4 + 3 < E) {
        int4 s4 = *(const int4*)(src + i4);
        int4 d4 = *(const int4*)(dst + i4);
        uchar4 l4 = *(const uchar4*)(loc + i4);
        csr[rowstart[d4.x] + l4.x] = s4.x;
        csr[rowstart[d4.y] + l4.y] = s4.y;
        csr[rowstart[d4.z] + l4.z] = s4.z;
        csr[rowstart[d4.w] + l4.w] = s4.w;
    } else {
        for (int i = i4; i < E; ++i) csr[rowstart[dst[i]] + loc[i]] = src[i];
    }
}

// ---------------- fuse weights: WfT(bf16) = (W1@[Wmu|Wls])^T, bb, bcat ------
__global__ __launch_bounds__(256) void fuse_w(const float* __restrict__ W1,
                                              const float* __restrict__ Wmu,
                                              const float* __restrict__ Wls,
                                              const float* __restrict__ b1,
                                              const float* __restrict__ bmu,
                                              const float* __restrict__ bls,
                                              u16* __restrict__ WfT,
                                              float* __restrict__ bb,
                                              float* __restrict__ bcat) {
    int idx = blockIdx.x * 256 + threadIdx.x;  // 16384
    if (idx >= 16384) return;
    int k = idx >> 7, n = idx & 127;
    const float* Wcol = (n < 64) ? (Wmu + n) : (Wls + (n - 64));
    float acc = 0.f;
#pragma unroll 8
    for (int j = 0; j < 128; ++j) acc += W1[k * 128 + j] * Wcol[j * 64];
    WfT[n * 128 + k] = f2bf(acc);  // transposed, bf16
    if (k == 0) {
        float accb = 0.f;
#pragma unroll 8
        for (int j = 0; j < 128; ++j) accb += b1[j] * Wcol[j * 64];
        bb[n] = accb;
        bcat[n] = (n < 64) ? bmu[n] : bls[n - 64];
    }
}

// ---------------- xs = bf16(x * dis[node]) ; zero row N in xs and ts --------
__global__ __launch_bounds__(256) void convert_x(const float* __restrict__ x,
                                                 const float* __restrict__ dis,
                                                 u32* __restrict__ xs,
                                                 u32* __restrict__ ts, int N) {
    long i = (long)blockIdx.x * 256 + threadIdx.x;  // (N+1)*32 threads
    long node = i >> 5;
    if (node > N) return;
    if (node == N) {  // zero row for branch-free dummy reads
        ((uint2*)xs)[i] = make_uint2(0u, 0u);
        ((uint2*)ts)[i] = make_uint2(0u, 0u);
        return;
    }
    float dd = dis[node];
    f32x4 v = ((const f32x4*)x)[i];
    u32 p0 = (u32)f2bf(v[0] * dd) | ((u32)f2bf(v[1] * dd) << 16);
    u32 p1 = (u32)f2bf(v[2] * dd) | ((u32)f2bf(v[3] * dd) << 16);
    ((uint2*)xs)[i] = make_uint2(p0, p1);
}

// ---------------- fused gather1 + GEMM + bb + dis-scale ---------------------
// Block = 16 nodes. Phase 1: gather y = xs[d] + sum xs[s] (4 nodes/wave,
// 16 lanes/node, 8-deep staged uint4 loads, csr prefetch) -> bf16 LDS tile
// (scaled by dd). Phase 2: ts[16x128] = bf16((y@Wf + bb) * dis) via MFMA,
// wave w covers cols [32w,32w+32), B-frags straight from L1-resident WfT.
__global__ __launch_bounds__(256) void g1gemm(const u32* __restrict__ xs,
                                              const int* __restrict__ csr,
                                              const u32* __restrict__ rowstart,
                                              const float* __restrict__ dis,
                                              const u16* __restrict__ WfT,
                                              const float* __restrict__ bb,
                                              u16* __restrict__ ts, int N) {
    __shared__ __align__(16) u16 ytile[16][136];  // 272B rows (16B aligned)
    __shared__ float disS[16];
    int tid = threadIdx.x, blk = blockIdx.x;
    int wave = tid >> 6, lane = tid & 63;
    int sub = lane >> 4, l = lane & 15;
    int nl = wave * 4 + sub;          // node_local 0..15
    int node = blk * 16 + nl;
    bool live = node < N;
    int nodeC = live ? node : 0;
    float dd = dis[nodeC];
    u32 beg = live ? rowstart[nodeC] : 0u;
    u32 end = live ? rowstart[nodeC + 1] : 0u;
    if (tid < 16) disS[tid] = (blk * 16 + tid < N) ? dis[blk * 16 + tid] : 0.f;

    const uint4* xs4 = (const uint4*)xs;
    uint4 selfv = xs4[(long)nodeC * 16 + l];
    float a0 = bflo(selfv.x), a1 = bfhi(selfv.x);
    float a2 = bflo(selfv.y), a3 = bfhi(selfv.y);
    float a4 = bflo(selfv.z), a5 = bfhi(selfv.z);
    float a6 = bflo(selfv.w), a7 = bfhi(selfv.w);

    int s = (beg + (u32)l < end) ? csr[beg + l] : N;
    for (u32 e0 = beg; e0 < end; e0 += 16) {
        u32 e1 = e0 + 16;
        int sn = (e1 < end && e1 + (u32)l < end) ? csr[e1 + l] : N;
#pragma unroll
        for (int h = 0; h < 2; ++h) {
            int sj[8]; uint4 w[8];
#pragma unroll
            for (int j = 0; j < 8; ++j) sj[j] = __shfl(s, sub * 16 + h * 8 + j);
#pragma unroll
            for (int j = 0; j < 8; ++j) w[j] = xs4[(long)sj[j] * 16 + l];
#pragma unroll
            for (int j = 0; j < 8; ++j) {
                a0 += bflo(w[j].x); a1 += bfhi(w[j].x);
                a2 += bflo(w[j].y); a3 += bfhi(w[j].y);
                a4 += bflo(w[j].z); a5 += bfhi(w[j].z);
                a6 += bflo(w[j].w); a7 += bfhi(w[j].w);
            }
        }
        s = sn;
    }
    uint4 o = make_uint4(0u, 0u, 0u, 0u);
    if (live) {
        o.x = (u32)f2bf(a0 * dd) | ((u32)f2bf(a1 * dd) << 16);
        o.y = (u32)f2bf(a2 * dd) | ((u32)f2bf(a3 * dd) << 16);
        o.z = (u32)f2bf(a4 * dd) | ((u32)f2bf(a5 * dd) << 16);
        o.w = (u32)f2bf(a6 * dd) | ((u32)f2bf(a7 * dd) << 16);
    }
    *(uint4*)&ytile[nl][l * 8] = o;
    __syncthreads();

    // ---- MFMA phase: rows 0..15 (shared), cols wave*32 .. wave*32+31 ----
    int quad = sub, mn = l;
    bf16x8 af[4];  // A[m=mn][k = kk*32 + quad*8 + j]
#pragma unroll
    for (int kk = 0; kk < 4; ++kk)
        af[kk] = *reinterpret_cast<const bf16x8*>(&ytile[mn][kk * 32 + quad * 8]);

#pragma unroll
    for (int n0 = 0; n0 < 2; ++n0) {
        int col = wave * 32 + n0 * 16 + mn;
        f32x4 acc = {0.f, 0.f, 0.f, 0.f};
#pragma unroll
        for (int kk = 0; kk < 4; ++kk) {
            bf16x8 bf =
                *reinterpret_cast<const bf16x8*>(&WfT[col * 128 + kk * 32 + quad * 8]);
            acc = __builtin_amdgcn_mfma_f32_16x16x32_bf16(af[kk], bf, acc, 0, 0, 0);
        }
        float bc = bb[col];
#pragma unroll
        for (int r = 0; r < 4; ++r) {  // C/D: col=lane&15(+16*n0), row=quad*4+r
            int row = quad * 4 + r;
            int gn = blk * 16 + row;
            if (gn < N) ts[(long)gn * 128 + col] = f2bf((acc[r] + bc) * disS[row]);
        }
    }
}

// ---------------- gather2 + bcat + reparam ----------------------------------
// val = dd*(ts[d] + sum_s ts[s]) + bcat ; cols 0..63 mu, 64..127 ls.
__global__ __launch_bounds__(256) void gather2(const u32* __restrict__ ts,
                                               const int* __restrict__ csr,
                                               const u32* __restrict__ rowstart,
                                               const float* __restrict__ dis,
                                               const float* __restrict__ bcat,
                                               const float* __restrict__ eps,
                                               float* __restrict__ out, int N) {
    int wid = (blockIdx.x * 256 + threadIdx.x) >> 6;
    int sub = (threadIdx.x & 63) >> 4, l = threadIdx.x & 15;
    int node = wid * 4 + sub;
    bool live = node < N;
    int nodeC = live ? node : 0;
    float dd = dis[nodeC];
    u32 beg = live ? rowstart[nodeC] : 0u;
    u32 end = live ? rowstart[nodeC + 1] : 0u;
    const uint4* ts4 = (const uint4*)ts;

    uint4 selfv = ts4[(long)nodeC * 16 + l];
    float a0 = bflo(selfv.x), a1 = bfhi(selfv.x);
    float a2 = bflo(selfv.y), a3 = bfhi(selfv.y);
    float a4 = bflo(selfv.z), a5 = bfhi(selfv.z);
    float a6 = bflo(selfv.w), a7 = bfhi(selfv.w);

    int s = (beg + (u32)l < end) ? csr[beg + l] : N;
    for (u32 e0 = beg; e0 < end; e0 += 16) {
        u32 e1 = e0 + 16;
        int sn = (e1 < end && e1 + (u32)l < end) ? csr[e1 + l] : N;
#pragma unroll
        for (int h = 0; h < 2; ++h) {
            int sj[8]; uint4 w[8];
#pragma unroll
            for (int j = 0; j < 8; ++j) sj[j] = __shfl(s, sub * 16 + h * 8 + j);
#pragma unroll
            for (int j = 0; j < 8; ++j) w[j] = ts4[(long)sj[j] * 16 + l];
#pragma unroll
            for (int j = 0; j < 8; ++j) {
                a0 += bflo(w[j].x); a1 += bfhi(w[j].x);
                a2 += bflo(w[j].y); a3 += bfhi(w[j].y);
                a4 += bflo(w[j].z); a5 += bfhi(w[j].z);
                a6 += bflo(w[j].w); a7 += bfhi(w[j].w);
            }
        }
        s = sn;
    }

    int c0 = l * 8;  // cols c0..c0+7 (l<8: mu cols c0; l>=8: ls cols c0-64)
    f32x4 clo = ((const f32x4*)bcat)[2 * l], chi = ((const f32x4*)bcat)[2 * l + 1];
    float v0 = a0 * dd + clo[0];
    float v1 = a1 * dd + clo[1];
    float v2 = a2 * dd + clo[2];
    float v3 = a3 * dd + clo[3];
    float v4 = a4 * dd + chi[0];
    float v5 = a5 * dd + chi[1];
    float v6 = a6 * dd + chi[2];
    float v7 = a7 * dd + chi[3];

    // ls values live 8 lanes up within the wave (same subgroup, l+8).
    int srcl = (threadIdx.x & 63) + 8;
    float w0 = __shfl(v0, srcl), w1 = __shfl(v1, srcl), w2 = __shfl(v2, srcl),
          w3 = __shfl(v3, srcl), w4 = __shfl(v4, srcl), w5 = __shfl(v5, srcl),
          w6 = __shfl(v6, srcl), w7 = __shfl(v7, srcl);

    if (!live) return;
    long NO = (long)N * 64;
    if (l < 8) {  // mu cols c0..c0+7 ; also compute z
        float* mu = out + NO + (long)node * 64 + c0;
        ((f32x4*)mu)[0] = f32x4{v0, v1, v2, v3};
        ((f32x4*)mu)[1] = f32x4{v4, v5, v6, v7};
        const float* ep = eps + (long)node * 64 + c0;
        f32x4 e0v = ((const f32x4*)ep)[0], e1v = ((const f32x4*)ep)[1];
        float* z = out + (long)node * 64 + c0;
        ((f32x4*)z)[0] = f32x4{v0 + e0v[0] * __expf(w0), v1 + e0v[1] * __expf(w1),
                               v2 + e0v[2] * __expf(w2), v3 + e0v[3] * __expf(w3)};
        ((f32x4*)z)[1] = f32x4{v4 + e1v[0] * __expf(w4), v5 + e1v[1] * __expf(w5),
                               v6 + e1v[2] * __expf(w6), v7 + e1v[3] * __expf(w7)};
    } else {      // logstd cols (c0-64)..(c0-64+7)
        float* ls = out + 2 * NO + (long)node * 64 + (c0 - 64);
        ((f32x4*)ls)[0] = f32x4{v0, v1, v2, v3};
        ((f32x4*)ls)[1] = f32x4{v4, v5, v6, v7};
    }
}

// ---------------------------------------------------------------------------
extern "C" void kernel_launch(void* const* d_in, const int* in_sizes, int n_in,
                              void* d_out, int out_size, void* d_ws, size_t ws_size,
                              hipStream_t stream) {
    const float* x   = (const float*)d_in[0];
    const int* ei    = (const int*)d_in[1];
    const float* W1  = (const float*)d_in[2];
    const float* b1  = (const float*)d_in[3];
    const float* Wmu = (const float*)d_in[4];
    const float* bmu = (const float*)d_in[5];
    const float* Wls = (const float*)d_in[6];
    const float* bls = (const float*)d_in[7];
    const float* eps = (const float*)d_in[8];
    float* out = (float*)d_out;

    const int N = in_sizes[0] / 128;   // 100000
    const int E = in_sizes[1] / 2;     // 1600000
    const int* src = ei;
    const int* dst = ei + E;
    const int NB = (N + 255) / 256;    // 391

    // WS layout (bytes), total ~60.4 MB.
    char* ws = (char*)d_ws;
    u32* deg       = (u32*)(ws + 0);         //   400,000
    u32* rowstart  = (u32*)(ws + 401408);    //   400,004
    u32* blockSums = (u32*)(ws + 802816);    //     2,048
    u32* blockOffs = (u32*)(ws + 804864);    //     2,048
    float* dis     = (float*)(ws + 806912);  //   400,000
    u16* WfT       = (u16*)(ws + 1208320);   //    32,768 (bf16, transposed)
    float* bb      = (float*)(ws + 1241088); //       512
    float* bcat    = (float*)(ws + 1241600); //       512
    u8* loc        = (u8*)(ws + 1242112);    // 1,600,000
    int* csr       = (int*)(ws + 2842112);   // 6,400,000
    u32* xs        = (u32*)(ws + 9242112);   // 25,600,256 ((N+1) rows bf16)
    u32* ts        = (u32*)(ws + 34842368);  // 25,600,256 ((N+1) rows bf16)

    hipMemsetAsync(deg, 0, 400000, stream);

    int gridE4 = (E / 4 + 255) / 256;
    deg_hist<<<gridE4, 256, 0, stream>>>(dst, deg, loc, E);
    scanA<<<NB, 256, 0, stream>>>(deg, blockSums, N);
    scanB<<<1, 512, 0, stream>>>(blockSums, blockOffs, NB);
    scanC<<<NB, 256, 0, stream>>>(deg, blockOffs, rowstart, dis, N, E);
    place_kernel<<<gridE4, 256, 0, stream>>>(src, dst, loc, rowstart, csr, E);
    fuse_w<<<64, 256, 0, stream>>>(W1, Wmu, Wls, b1, bmu, bls, WfT, bb, bcat);

    long Qc = (long)(N + 1) * 32;  // uint2-granular threads incl. zero row
    convert_x<<<(int)((Qc + 255) / 256), 256, 0, stream>>>(x, dis, xs, ts, N);

    int gridT = (N + 15) / 16;                    // 16 nodes per block
    g1gemm<<<gridT, 256, 0, stream>>>(xs, csr, rowstart, dis, WfT, bb,
                                      (u16*)ts, N);

    int gridG = ((N + 3) / 4 * 64 + 255) / 256;   // 1 wave / 4 nodes
    gather2<<<gridG, 256, 0, stream>>>(ts, csr, rowstart, dis, bcat, eps, out, N);
}